// Round 5
// baseline (564.143 us; speedup 1.0000x reference)
//
#include <hip/hip_runtime.h>
#include <cstdint>
#include <cstddef>

typedef unsigned short u16;
typedef unsigned int u32;
typedef short bf16x8 __attribute__((ext_vector_type(8)));
typedef float f32x4 __attribute__((ext_vector_type(4)));
typedef float f32x16 __attribute__((ext_vector_type(16)));
typedef u16 u16x4 __attribute__((ext_vector_type(4)));

__device__ __forceinline__ u16 f2bf(float f) {
  u32 u = __float_as_uint(f);
  return (u16)((u + 0x7FFFu + ((u >> 16) & 1u)) >> 16);
}
__device__ __forceinline__ float bf2f(u16 h) {
  return __uint_as_float(((u32)h) << 16);
}
__device__ __forceinline__ u32 pack2(float a, float b) {
  return (u32)f2bf(a) | ((u32)f2bf(b) << 16);
}

__device__ __forceinline__ void gload_lds16(const void* g, void* l) {
  __builtin_amdgcn_global_load_lds((const __attribute__((address_space(1))) u32*)g,
                                   (__attribute__((address_space(3))) u32*)l, 16, 0, 0);
}

// inline-asm LDS read: no memory operand -> the waitcnt pass cannot attach
// alias-conservative vmcnt waits (LDS-DMA in flight) to it. Ordering is done
// manually via lgkmcnt + sched_barrier per rule #18.
typedef const __attribute__((address_space(3))) u16* lds_cp;
__device__ __forceinline__ bf16x8 dsr128(const void* p) {
  bf16x8 d;
  asm volatile("ds_read_b128 %0, %1" : "=&v"(d) : "v"((lds_cp)p));
  return d;
}

// ---------------- weight cast fp32 -> bf16 ----------------
__global__ __launch_bounds__(256) void castw(const float* __restrict__ src,
                                             u16* __restrict__ dst, int n4) {
  int i = blockIdx.x * 256 + threadIdx.x;
  if (i < n4) {
    float4 v = ((const float4*)src)[i];
    u16x4 r;
    r.x = f2bf(v.x); r.y = f2bf(v.y); r.z = f2bf(v.z); r.w = f2bf(v.w);
    ((u16x4*)dst)[i] = r;
  }
}

// ---------------- RMSNorm: fp32 [rows,1024] -> bf16 ----------------
__global__ __launch_bounds__(256) void rmsnorm_k(const float* __restrict__ x,
                                                 const float* __restrict__ gamma,
                                                 u16* __restrict__ o) {
  const int row = blockIdx.x;
  const int t = threadIdx.x;
  float4 v = ((const float4*)(x + (size_t)row * 1024))[t];
  float ss = v.x * v.x + v.y * v.y + v.z * v.z + v.w * v.w;
  #pragma unroll
  for (int m = 1; m < 64; m <<= 1) ss += __shfl_xor(ss, m);
  __shared__ float wsum[4];
  if ((t & 63) == 0) wsum[t >> 6] = ss;
  __syncthreads();
  float tot = wsum[0] + wsum[1] + wsum[2] + wsum[3];
  float inv = rsqrtf(tot * (1.0f / 1024.0f) + 1e-5f);
  float4 g = ((const float4*)gamma)[t];
  u16x4 r;
  r.x = f2bf(v.x * inv * g.x);
  r.y = f2bf(v.y * inv * g.y);
  r.z = f2bf(v.z * inv * g.z);
  r.w = f2bf(v.w * inv * g.w);
  ((u16x4*)(o + (size_t)row * 1024))[t] = r;
}

// ========== 256x256 8-phase GEMM: C[M,N] = A[M,K] * B[N,K]^T ==========
// EPI 0: bf16 = acc * (col<ncut?scale:1)
// EPI 2: bf16 = silu(ep[idx]) * acc
// EPI 3: fp32 unsafeAtomicAdd(out+idx, acc)   (split-K slices via blockIdx.z)
template <int EPI>
__global__ __launch_bounds__(512, 2)
void gemm256(const u16* __restrict__ A, const u16* __restrict__ B,
             void* out, const void* ep, int M, int N, int KLOOP, int KS,
             float scale, int ncut) {
  __shared__ u16 smA[2][16384];   // [buf][256 rows x 64]
  __shared__ u16 smB[2][16384];

  const int tid = threadIdx.x;
  const int lane = tid & 63;
  const int w = tid >> 6;
  const int wm = w >> 2, wn = w & 3;
  const int lr = lane & 15, lk = lane >> 4;

  // split-K offset
  A += (size_t)blockIdx.z * KLOOP;
  B += (size_t)blockIdx.z * KLOOP;

  // bijective XCD swizzle (m204) + 2D chunking (8 m-rows per super-row)
  const int nx = gridDim.x;
  const int nwg = nx * gridDim.y;
  const int flat = blockIdx.y * nx + blockIdx.x;
  const int qq = nwg >> 3, rr = nwg & 7;
  const int xcd = flat & 7, off = flat >> 3;
  const int swz = (xcd < rr ? xcd * (qq + 1) : rr * (qq + 1) + (xcd - rr) * qq) + off;
  const int sr = nx * 8;
  const int g8 = swz / sr, rem = swz % sr;
  const int m0 = (g8 * 8 + (rem & 7)) * 256;
  const int n0 = (rem >> 3) * 256;

  // staging geometry: one block-wide gload covers 64 rows (8KB)
  const int srow = w * 8 + (lane >> 3);
  const int sch8 = (((lane & 7) ^ ((lane >> 3) & 7)) << 3);

  // read geometry
  const int rA = wm * 128 + lr;
  const int rB = wn * 64 + lr;
  const int kc0 = (lk ^ (lr & 7)) << 4;
  const int kc1 = kc0 ^ 64;

  const int NT = KLOOP >> 6;

  #define STAGE_A(BUF, q, U) gload_lds16(A + (size_t)(m0 + (q) * 64 + srow) * KS + ((U) << 6) + sch8, \
                                         (char*)smA[BUF] + (q) * 8192 + w * 1024)
  #define STAGE_B(BUF, q, U) gload_lds16(B + (size_t)(n0 + (q) * 64 + srow) * KS + ((U) << 6) + sch8, \
                                         (char*)smB[BUF] + (q) * 8192 + w * 1024)

  // prologue: stage tiles 0 and 1
  #pragma unroll
  for (int q = 0; q < 4; q++) STAGE_A(0, q, 0);
  #pragma unroll
  for (int q = 0; q < 4; q++) STAGE_B(0, q, 0);
  #pragma unroll
  for (int q = 0; q < 4; q++) STAGE_A(1, q, 1);
  #pragma unroll
  for (int q = 0; q < 4; q++) STAGE_B(1, q, 1);
  asm volatile("s_waitcnt vmcnt(8)");
  __builtin_amdgcn_sched_barrier(0);
  __builtin_amdgcn_s_barrier();

  f32x4 acc[8][4];
  #pragma unroll
  for (int i = 0; i < 8; i++)
    #pragma unroll
    for (int j = 0; j < 4; j++) acc[i][j] = (f32x4){0.f, 0.f, 0.f, 0.f};

  bf16x8 af[4][2], bfa[2][2], bfb[2][2];

  #define MFMA_QUAD(I0, J0, AF, BF)                                                            \
    __builtin_amdgcn_s_setprio(1);                                                             \
    _Pragma("unroll")                                                                          \
    for (int i = 0; i < 4; i++)                                                                \
      _Pragma("unroll")                                                                        \
      for (int j = 0; j < 2; j++) {                                                            \
        acc[(I0) + i][(J0) + j] = __builtin_amdgcn_mfma_f32_16x16x32_bf16(                     \
            AF[i][0], BF[j][0], acc[(I0) + i][(J0) + j], 0, 0, 0);                             \
        acc[(I0) + i][(J0) + j] = __builtin_amdgcn_mfma_f32_16x16x32_bf16(                     \
            AF[i][1], BF[j][1], acc[(I0) + i][(J0) + j], 0, 0, 0);                             \
      }                                                                                        \
    __builtin_amdgcn_s_setprio(0);

  #define K_ITER(BUF, WC)                                                                      \
  {                                                                                            \
    const bool st = ((WC) + 2 < NT);                                                           \
    const int U = (WC) + 2;                                                                    \
    const char* pA = (const char*)smA[BUF] + rA * 128;                                         \
    const char* pB = (const char*)smB[BUF] + rB * 128;                                         \
    /* P0: read A(ih0)+B(jh0) */                                                               \
    _Pragma("unroll")                                                                          \
    for (int i = 0; i < 4; i++) {                                                              \
      af[i][0] = dsr128(pA + i * 2048 + kc0);                                                  \
      af[i][1] = dsr128(pA + i * 2048 + kc1);                                                  \
    }                                                                                          \
    _Pragma("unroll")                                                                          \
    for (int j = 0; j < 2; j++) {                                                              \
      bfa[j][0] = dsr128(pB + j * 2048 + kc0);                                                 \
      bfa[j][1] = dsr128(pB + j * 2048 + kc1);                                                 \
    }                                                                                          \
    asm volatile("s_waitcnt lgkmcnt(8)");                                                      \
    __builtin_amdgcn_s_barrier();                                                              \
    asm volatile("s_waitcnt lgkmcnt(0)");                                                      \
    __builtin_amdgcn_sched_barrier(0);                                                         \
    MFMA_QUAD(0, 0, af, bfa)                                                                   \
    __builtin_amdgcn_s_barrier();                                                              \
    /* P1: read B(jh1); stage A(U) q0,q2 */                                                    \
    _Pragma("unroll")                                                                          \
    for (int j = 0; j < 2; j++) {                                                              \
      bfb[j][0] = dsr128(pB + (j + 2) * 2048 + kc0);                                           \
      bfb[j][1] = dsr128(pB + (j + 2) * 2048 + kc1);                                           \
    }                                                                                          \
    if (st) { STAGE_A(BUF, 0, U); STAGE_A(BUF, 2, U); }                                        \
    __builtin_amdgcn_s_barrier();                                                              \
    asm volatile("s_waitcnt lgkmcnt(0)");                                                      \
    __builtin_amdgcn_sched_barrier(0);                                                         \
    MFMA_QUAD(0, 2, af, bfb)                                                                   \
    __builtin_amdgcn_s_barrier();                                                              \
    /* P2: read A(ih1); stage B(U) q0..q3 */                                                   \
    _Pragma("unroll")                                                                          \
    for (int i = 0; i < 4; i++) {                                                              \
      af[i][0] = dsr128(pA + (i + 4) * 2048 + kc0);                                            \
      af[i][1] = dsr128(pA + (i + 4) * 2048 + kc1);                                            \
    }                                                                                          \
    if (st) { STAGE_B(BUF, 0, U); STAGE_B(BUF, 1, U); STAGE_B(BUF, 2, U); STAGE_B(BUF, 3, U); }\
    __builtin_amdgcn_s_barrier();                                                              \
    asm volatile("s_waitcnt lgkmcnt(0)");                                                      \
    __builtin_amdgcn_sched_barrier(0);                                                         \
    MFMA_QUAD(4, 0, af, bfa)                                                                   \
    __builtin_amdgcn_s_barrier();                                                              \
    /* P3: stage A(U) q1,q3 */                                                                 \
    if (st) { STAGE_A(BUF, 1, U); STAGE_A(BUF, 3, U); }                                        \
    __builtin_amdgcn_s_barrier();                                                              \
    __builtin_amdgcn_sched_barrier(0);                                                         \
    MFMA_QUAD(4, 2, af, bfb)                                                                   \
    if (st) { asm volatile("s_waitcnt vmcnt(8)"); }                                            \
    else    { asm volatile("s_waitcnt vmcnt(0)"); }                                            \
    __builtin_amdgcn_sched_barrier(0);                                                         \
    __builtin_amdgcn_s_barrier();                                                              \
  }

  for (int W = 0; W < NT; W += 2) {
    K_ITER(0, W)
    K_ITER(1, W + 1)
  }

  #undef K_ITER
  #undef MFMA_QUAD
  #undef STAGE_A
  #undef STAGE_B

  // epilogue
  #pragma unroll
  for (int i = 0; i < 8; i++)
    #pragma unroll
    for (int j = 0; j < 4; j++)
      #pragma unroll
      for (int r = 0; r < 4; r++) {
        const int grow = m0 + wm * 128 + i * 16 + lk * 4 + r;
        const int gcol = n0 + wn * 64 + j * 16 + lr;
        const size_t idx = (size_t)grow * N + gcol;
        const float val = acc[i][j][r];
        if (EPI == 0) {
          const float s = (gcol < ncut) ? scale : 1.0f;
          ((u16*)out)[idx] = f2bf(val * s);
        } else if (EPI == 2) {
          float gv = bf2f(((const u16*)ep)[idx]);
          float sg = gv / (1.f + __expf(-gv));
          ((u16*)out)[idx] = f2bf(sg * val);
        } else {
          unsafeAtomicAdd((float*)out + idx, val);
        }
      }
}

// ---------------- legacy 128x128 GEMM (o-proj) ----------------
// EPI 1: out fp32 = acc + ep_fp32[idx]
template <int EPI>
__global__ __launch_bounds__(256, 2)
void gemm_bt(const u16* __restrict__ A, const u16* __restrict__ B,
             void* out, const void* ep, int M, int N, int K, float scale) {
  __shared__ u16 As[128 * 32];
  __shared__ u16 Bs[128 * 32];
  const int tid = threadIdx.x;
  const int lane = tid & 63;
  const int w = tid >> 6;
  const int wr = w >> 1, wc = w & 1;
  const int nx = gridDim.x;
  const int nwg = nx * gridDim.y;
  const int flat = blockIdx.y * nx + blockIdx.x;
  const int swz = (flat & 7) * (nwg >> 3) + (flat >> 3);
  const int m0 = (swz / nx) * 128;
  const int n0 = (swz % nx) * 128;
  const int lr = lane & 15;
  const int lk = lane >> 4;
  const int srow = lane >> 2;
  const int scol = (lane & 3) * 8;

  const f32x4 zero4 = {0.f, 0.f, 0.f, 0.f};
  f32x4 acc[4][4];
  #pragma unroll
  for (int i = 0; i < 4; i++)
    #pragma unroll
    for (int j = 0; j < 4; j++) acc[i][j] = zero4;

  for (int kt = 0; kt < K; kt += 32) {
    __syncthreads();
    #pragma unroll
    for (int c = 0; c < 2; c++) {
      const int rbase = w * 32 + c * 16;
      gload_lds16(A + (size_t)(m0 + rbase + srow) * K + kt + scol, &As[rbase * 32]);
      gload_lds16(B + (size_t)(n0 + rbase + srow) * K + kt + scol, &Bs[rbase * 32]);
    }
    __syncthreads();
    bf16x8 af[4], bfr[4];
    #pragma unroll
    for (int i = 0; i < 4; i++)
      af[i] = *(const bf16x8*)&As[(wr * 64 + i * 16 + lr) * 32 + lk * 8];
    #pragma unroll
    for (int j = 0; j < 4; j++)
      bfr[j] = *(const bf16x8*)&Bs[(wc * 64 + j * 16 + lr) * 32 + lk * 8];
    #pragma unroll
    for (int i = 0; i < 4; i++)
      #pragma unroll
      for (int j = 0; j < 4; j++)
        acc[i][j] = __builtin_amdgcn_mfma_f32_16x16x32_bf16(af[i], bfr[j], acc[i][j], 0, 0, 0);
  }

  const int r0 = lk * 4;
  #pragma unroll
  for (int i = 0; i < 4; i++) {
    #pragma unroll
    for (int j = 0; j < 4; j++) {
      #pragma unroll
      for (int r = 0; r < 4; r++) {
        const int grow = m0 + wr * 64 + i * 16 + r0 + r;
        const int gcol = n0 + wc * 64 + j * 16 + lr;
        const size_t idx = (size_t)grow * N + gcol;
        const float val = acc[i][j][r];
        if (EPI == 0) {
          ((u16*)out)[idx] = f2bf(val * scale);
        } else if (EPI == 1) {
          ((float*)out)[idx] = ((const float*)ep)[idx] + val;
        } else {
          float gv = bf2f(((const u16*)ep)[idx]);
          float sg = gv / (1.f + __expf(-gv));
          ((u16*)out)[idx] = f2bf(sg * val);
        }
      }
    }
  }
}

// ---------------- V transpose from packed qkv: -> vt[bh=64][d=64][s=2048] ----
__global__ __launch_bounds__(256) void vtrans(const u16* __restrict__ qkv,
                                              u16* __restrict__ vt) {
  __shared__ u16 T[64][72];
  const int t = threadIdx.x;
  const int s0 = blockIdx.x * 64;
  const int h = blockIdx.y;
  const int b = blockIdx.z;
  const int sl = t >> 2, dl = (t & 3) * 16;
  const u16* src = qkv + ((size_t)(b * 2048 + s0 + sl)) * 3072 + 2048 + h * 64 + dl;
  bf16x8 v0 = *(const bf16x8*)src;
  bf16x8 v1 = *(const bf16x8*)(src + 8);
  #pragma unroll
  for (int j = 0; j < 8; j++) T[dl + j][sl] = (u16)v0[j];
  #pragma unroll
  for (int j = 0; j < 8; j++) T[dl + 8 + j][sl] = (u16)v1[j];
  __syncthreads();
  const int dl2 = t >> 2, sl2 = (t & 3) * 16;
  u16* dst = vt + ((size_t)((b * 16 + h) * 64 + dl2)) * 2048 + s0 + sl2;
  *(bf16x8*)dst = *(const bf16x8*)&T[dl2][sl2];
  *(bf16x8*)(dst + 8) = *(const bf16x8*)&T[dl2][sl2 + 8];
}

// ---------------- causal flash attention (packed qkv input) ----------------
__global__ __launch_bounds__(256)
void attn_fwd2(const u16* __restrict__ qkv, const u16* __restrict__ vt,
               u16* __restrict__ o) {
  __shared__ u16 sm[9216];
  u16* const smK = sm;
  u16* const smV = sm + 4096;

  const int tid = threadIdx.x;
  const int lane = tid & 63;
  const int w = tid >> 6;
  const int hi = lane >> 5;
  const int ln = lane & 31;

  const int flat = blockIdx.y * 16 + blockIdx.x;
  const int swz = (flat & 7) * 128 + (flat >> 3);
  const int qt = swz & 15;
  const int bh = swz >> 4;
  const int b = bh >> 4, h = bh & 15;

  const int qbase = qt * 128;
  const int qw0 = qbase + w * 32;
  const int qglob = qw0 + ln;
  const int nkb = qt * 2 + 2;

  bf16x8 qf[4];
  {
    const u16* qp = qkv + ((size_t)(b * 2048 + qw0 + ln)) * 3072 + h * 64 + hi * 8;
    #pragma unroll
    for (int c = 0; c < 4; c++) qf[c] = *(const bf16x8*)(qp + c * 16);
  }

  f32x16 accO[2];
  #pragma unroll
  for (int i = 0; i < 2; i++)
    #pragma unroll
    for (int r = 0; r < 16; r++) accO[i][r] = 0.f;
  float mrun = -1e30f, lsum = 0.f;

  for (int kb = 0; kb < nkb; kb++) {
    const int kbase = kb * 64;
    __syncthreads();
    #pragma unroll
    for (int r = 0; r < 2; r++) {
      const int cb = w * 128 + r * 64;
      const int ci = cb + lane;
      {
        const int key = ci >> 3, gch = (ci & 7) ^ (key & 7);
        const u16* src = qkv + ((size_t)(b * 2048 + kbase + key)) * 3072 + 1024 + h * 64 + gch * 8;
        gload_lds16(src, (char*)smK + cb * 16);
      }
      {
        const int d = ci >> 3, gch = (ci & 7) ^ (d & 7);
        const u16* src = vt + ((size_t)(bh * 64 + d)) * 2048 + kbase + gch * 8;
        gload_lds16(src, (char*)smV + cb * 16);
      }
    }
    __syncthreads();

    if (kbase <= qw0 + 31) {
      f32x16 st[2];
      #pragma unroll
      for (int kt = 0; kt < 2; kt++) {
        #pragma unroll
        for (int r = 0; r < 16; r++) st[kt][r] = 0.f;
        #pragma unroll
        for (int c = 0; c < 4; c++) {
          const int row = kt * 32 + ln;
          const int sch = (c * 2 + hi) ^ (ln & 7);
          bf16x8 kf = *(const bf16x8*)((const char*)smK + row * 128 + sch * 16);
          st[kt] = __builtin_amdgcn_mfma_f32_32x32x16_bf16(kf, qf[c], st[kt], 0, 0, 0);
        }
      }
      if (kbase + 63 > qw0) {
        #pragma unroll
        for (int kt = 0; kt < 2; kt++)
          #pragma unroll
          for (int r = 0; r < 16; r++) {
            const int kk = kbase + kt * 32 + (r & 3) + 8 * (r >> 2) + 4 * hi;
            if (kk > qglob) st[kt][r] = -1e30f;
          }
      }
      float pm = st[0][0];
      #pragma unroll
      for (int kt = 0; kt < 2; kt++)
        #pragma unroll
        for (int r = 0; r < 16; r++) pm = fmaxf(pm, st[kt][r]);
      pm = fmaxf(pm, __shfl_xor(pm, 32));
      const float mnew = fmaxf(mrun, pm);
      const float alpha = __expf(mrun - mnew);
      float ps = 0.f;
      #pragma unroll
      for (int kt = 0; kt < 2; kt++)
        #pragma unroll
        for (int r = 0; r < 16; r++) {
          const float p = __expf(st[kt][r] - mnew);
          st[kt][r] = p;
          ps += p;
        }
      ps += __shfl_xor(ps, 32);
      lsum = lsum * alpha + ps;
      mrun = mnew;
      accO[0] *= alpha;
      accO[1] *= alpha;

      #pragma unroll
      for (int kt = 0; kt < 2; kt++) {
        u32 pw[8], px[8];
        #pragma unroll
        for (int i = 0; i < 8; i++) pw[i] = pack2(st[kt][2 * i], st[kt][2 * i + 1]);
        #pragma unroll
        for (int i = 0; i < 8; i++) px[i] = (u32)__shfl_xor((int)pw[i], 32);
        union { u32 wd[4]; bf16x8 v; } f0, f1;
        f0.wd[0] = hi ? px[2] : pw[0];
        f0.wd[1] = hi ? px[3] : pw[1];
        f0.wd[2] = hi ? pw[2] : px[0];
        f0.wd[3] = hi ? pw[3] : px[1];
        f1.wd[0] = hi ? px[6] : pw[4];
        f1.wd[1] = hi ? px[7] : pw[5];
        f1.wd[2] = hi ? pw[6] : px[4];
        f1.wd[3] = hi ? pw[7] : px[5];
        #pragma unroll
        for (int d0 = 0; d0 < 2; d0++) {
          #pragma unroll
          for (int kc = 0; kc < 2; kc++) {
            const int drow = d0 * 32 + ln;
            const int sch = (kt * 4 + kc * 2 + hi) ^ (ln & 7);
            bf16x8 vf = *(const bf16x8*)((const char*)smV + drow * 128 + sch * 16);
            accO[d0] = __builtin_amdgcn_mfma_f32_32x32x16_bf16(vf, kc ? f1.v : f0.v,
                                                               accO[d0], 0, 0, 0);
          }
        }
      }
    }
  }

  __syncthreads();
  const float inv = 1.0f / lsum;
  #pragma unroll
  for (int d0 = 0; d0 < 2; d0++)
    #pragma unroll
    for (int r = 0; r < 16; r++) {
      const int d = d0 * 32 + (r & 3) + 8 * (r >> 2) + 4 * hi;
      sm[(w * 32 + ln) * 72 + d] = f2bf(accO[d0][r] * inv);
    }
  __syncthreads();
  const int ql = tid >> 1, dh = (tid & 1) * 32;
  const u16* srcp = &sm[ql * 72 + dh];
  u16* dst = o + ((size_t)(b * 2048 + qbase + ql)) * 1024 + h * 64 + dh;
  #pragma unroll
  for (int j = 0; j < 4; j++)
    *(bf16x8*)(dst + j * 8) = *(const bf16x8*)(srcp + j * 8);
}

// ---------------- host ----------------
extern "C" void kernel_launch(void* const* d_in, const int* in_sizes, int n_in,
                              void* d_out, int out_size, void* d_ws, size_t ws_size,
                              hipStream_t stream) {
  const float* x      = (const float*)d_in[0];
  const float* W_q    = (const float*)d_in[1];
  const float* W_k    = (const float*)d_in[2];
  const float* W_v    = (const float*)d_in[3];
  const float* W_o    = (const float*)d_in[4];
  const float* gamma1 = (const float*)d_in[5];
  const float* gamma2 = (const float*)d_in[6];
  const float* W1     = (const float*)d_in[7];
  const float* W2     = (const float*)d_in[8];
  const float* W3     = (const float*)d_in[9];

  char* ws = (char*)d_ws;
  const size_t MB = 1ull << 20;
  u16* qkvw  = (u16*)(ws + 0 * MB);    // Wq|Wk|Wv rows concat [3072][1024]
  u16* Wo_b  = (u16*)(ws + 6 * MB);
  u16* W1_b  = (u16*)(ws + 8 * MB);
  u16* W3_b  = (u16*)(ws + 16 * MB);
  u16* W2_b  = (u16*)(ws + 24 * MB);
  u16* xn    = (u16*)(ws + 32 * MB);   // 16 MB
  u16* qkvb  = (u16*)(ws + 48 * MB);   // [8192][3072] = 48 MB -> 48..96
  u16* attnb = (u16*)(ws + 96 * MB);   // 16 MB
  u16* vtb   = (u16*)(ws + 112 * MB);  // 16 MB (dead after attn)
  u16* gbuf  = (u16*)(ws + 112 * MB);  // 64 MB -> 112..176 (after attn)
  u16* hbuf  = (u16*)(ws + 48 * MB);   // 64 MB, reuses qkvb+attnb (dead)
  float* x1  = (float*)d_out;

  castw<<<1024, 256, 0, stream>>>(W_q, qkvw, 262144);
  castw<<<1024, 256, 0, stream>>>(W_k, qkvw + 1024 * 1024, 262144);
  castw<<<1024, 256, 0, stream>>>(W_v, qkvw + 2048 * 1024, 262144);
  castw<<<1024, 256, 0, stream>>>(W_o, Wo_b, 262144);
  castw<<<4096, 256, 0, stream>>>(W1, W1_b, 1048576);
  castw<<<4096, 256, 0, stream>>>(W3, W3_b, 1048576);
  castw<<<4096, 256, 0, stream>>>(W2, W2_b, 1048576);

  rmsnorm_k<<<8192, 256, 0, stream>>>(x, gamma1, xn);
  gemm256<0><<<dim3(12, 32), 512, 0, stream>>>(xn, qkvw, qkvb, nullptr,
                                               8192, 3072, 1024, 1024, 0.125f, 1024);
  vtrans<<<dim3(32, 16, 4), 256, 0, stream>>>(qkvb, vtb);
  attn_fwd2<<<dim3(16, 64), 256, 0, stream>>>(qkvb, vtb, attnb);
  gemm_bt<1><<<dim3(8, 64), 256, 0, stream>>>(attnb, Wo_b, x1, x, 8192, 1024, 1024, 1.0f);

  rmsnorm_k<<<8192, 256, 0, stream>>>(x1, gamma2, xn);
  gemm256<0><<<dim3(16, 32), 512, 0, stream>>>(xn, W1_b, gbuf, nullptr,
                                               8192, 4096, 1024, 1024, 1.0f, 0);
  gemm256<2><<<dim3(16, 32), 512, 0, stream>>>(xn, W3_b, hbuf, gbuf,
                                               8192, 4096, 1024, 1024, 1.0f, 0);
  // down-proj: split-K=2, fp32 atomic accumulate into d_out (holds x1)
  gemm256<3><<<dim3(4, 32, 2), 512, 0, stream>>>(hbuf, W2_b, (float*)d_out, nullptr,
                                                 8192, 1024, 2048, 4096, 1.0f, 0);
}

// Round 6
// 560.857 us; speedup vs baseline: 1.0059x; 1.0059x over previous
//
#include <hip/hip_runtime.h>
#include <cstdint>
#include <cstddef>

typedef unsigned short u16;
typedef unsigned int u32;
typedef short bf16x8 __attribute__((ext_vector_type(8)));
typedef float f32x4 __attribute__((ext_vector_type(4)));
typedef float f32x16 __attribute__((ext_vector_type(16)));
typedef u16 u16x4 __attribute__((ext_vector_type(4)));

__device__ __forceinline__ u16 f2bf(float f) {
  u32 u = __float_as_uint(f);
  return (u16)((u + 0x7FFFu + ((u >> 16) & 1u)) >> 16);
}
__device__ __forceinline__ float bf2f(u16 h) {
  return __uint_as_float(((u32)h) << 16);
}
__device__ __forceinline__ u32 pack2(float a, float b) {
  return (u32)f2bf(a) | ((u32)f2bf(b) << 16);
}

__device__ __forceinline__ void gload_lds16(const void* g, void* l) {
  __builtin_amdgcn_global_load_lds((const __attribute__((address_space(1))) u32*)g,
                                   (__attribute__((address_space(3))) u32*)l, 16, 0, 0);
}

// inline-asm LDS read: exact issue order + manual lgkmcnt bookkeeping.
typedef const __attribute__((address_space(3))) u16* lds_cp;
__device__ __forceinline__ bf16x8 dsr128(const void* p) {
  bf16x8 d;
  asm volatile("ds_read_b128 %0, %1" : "=&v"(d) : "v"((lds_cp)p));
  return d;
}

// ---------------- weight cast fp32 -> bf16 ----------------
__global__ __launch_bounds__(256) void castw(const float* __restrict__ src,
                                             u16* __restrict__ dst, int n4) {
  int i = blockIdx.x * 256 + threadIdx.x;
  if (i < n4) {
    float4 v = ((const float4*)src)[i];
    u16x4 r;
    r.x = f2bf(v.x); r.y = f2bf(v.y); r.z = f2bf(v.z); r.w = f2bf(v.w);
    ((u16x4*)dst)[i] = r;
  }
}

// ---------------- RMSNorm: fp32 [rows,1024] -> bf16 ----------------
__global__ __launch_bounds__(256) void rmsnorm_k(const float* __restrict__ x,
                                                 const float* __restrict__ gamma,
                                                 u16* __restrict__ o) {
  const int row = blockIdx.x;
  const int t = threadIdx.x;
  float4 v = ((const float4*)(x + (size_t)row * 1024))[t];
  float ss = v.x * v.x + v.y * v.y + v.z * v.z + v.w * v.w;
  #pragma unroll
  for (int m = 1; m < 64; m <<= 1) ss += __shfl_xor(ss, m);
  __shared__ float wsum[4];
  if ((t & 63) == 0) wsum[t >> 6] = ss;
  __syncthreads();
  float tot = wsum[0] + wsum[1] + wsum[2] + wsum[3];
  float inv = rsqrtf(tot * (1.0f / 1024.0f) + 1e-5f);
  float4 g = ((const float4*)gamma)[t];
  u16x4 r;
  r.x = f2bf(v.x * inv * g.x);
  r.y = f2bf(v.y * inv * g.y);
  r.z = f2bf(v.z * inv * g.z);
  r.w = f2bf(v.w * inv * g.w);
  ((u16x4*)(o + (size_t)row * 1024))[t] = r;
}

// ========== 256x256 GEMM, single-wave-pipelined reads: C = A * B^T ==========
// Per K-tile: issue all 24 ds_read_b128 up front, drain with counted
// lgkmcnt(12/8/0) so LDS reads + stage issues execute under the MFMA stream.
// 2 barriers/K-tile. Counted vmcnt(8) at tile end (never 0 mid-loop).
// EPI 0: bf16 = acc * (col<ncut?scale:1)
// EPI 2: bf16 = silu(ep[idx]) * acc
// EPI 3: fp32 unsafeAtomicAdd(out+idx, acc)   (split-K via blockIdx.z)
template <int EPI>
__global__ __launch_bounds__(512, 2)
void gemm256(const u16* __restrict__ A, const u16* __restrict__ B,
             void* out, const void* ep, int M, int N, int KLOOP, int KS,
             float scale, int ncut) {
  __shared__ u16 smA[2][16384];   // [buf][256 rows x 64]
  __shared__ u16 smB[2][16384];

  const int tid = threadIdx.x;
  const int lane = tid & 63;
  const int w = tid >> 6;
  const int wm = w >> 2, wn = w & 3;
  const int lr = lane & 15, lk = lane >> 4;

  A += (size_t)blockIdx.z * KLOOP;
  B += (size_t)blockIdx.z * KLOOP;

  // bijective XCD swizzle (m204) + 2D chunking (8 m-rows per super-row)
  const int nx = gridDim.x;
  const int nwg = nx * gridDim.y;
  const int flat = blockIdx.y * nx + blockIdx.x;
  const int qq = nwg >> 3, rr = nwg & 7;
  const int xcd = flat & 7, off = flat >> 3;
  const int swz = (xcd < rr ? xcd * (qq + 1) : rr * (qq + 1) + (xcd - rr) * qq) + off;
  const int sr = nx * 8;
  const int g8 = swz / sr, rem = swz % sr;
  const int m0 = (g8 * 8 + (rem & 7)) * 256;
  const int n0 = (rem >> 3) * 256;

  const int srow = w * 8 + (lane >> 3);
  const int sch8 = (((lane & 7) ^ ((lane >> 3) & 7)) << 3);

  const int rA = wm * 128 + lr;
  const int rB = wn * 64 + lr;
  const int kc0 = (lk ^ (lr & 7)) << 4;
  const int kc1 = kc0 ^ 64;

  const int NT = KLOOP >> 6;

  #define STAGE_A(BUF, q, U) gload_lds16(A + (size_t)(m0 + (q) * 64 + srow) * KS + ((U) << 6) + sch8, \
                                         (char*)smA[BUF] + (q) * 8192 + w * 1024)
  #define STAGE_B(BUF, q, U) gload_lds16(B + (size_t)(n0 + (q) * 64 + srow) * KS + ((U) << 6) + sch8, \
                                         (char*)smB[BUF] + (q) * 8192 + w * 1024)

  // prologue: stage tiles 0 and 1
  #pragma unroll
  for (int q = 0; q < 4; q++) STAGE_A(0, q, 0);
  #pragma unroll
  for (int q = 0; q < 4; q++) STAGE_B(0, q, 0);
  #pragma unroll
  for (int q = 0; q < 4; q++) STAGE_A(1, q, 1);
  #pragma unroll
  for (int q = 0; q < 4; q++) STAGE_B(1, q, 1);
  asm volatile("s_waitcnt vmcnt(8)");
  asm volatile("s_waitcnt lgkmcnt(0)");   // drain arg s_loads so counts are exact
  __builtin_amdgcn_sched_barrier(0);
  __builtin_amdgcn_s_barrier();

  f32x4 acc[8][4];
  #pragma unroll
  for (int i = 0; i < 8; i++)
    #pragma unroll
    for (int j = 0; j < 4; j++) acc[i][j] = (f32x4){0.f, 0.f, 0.f, 0.f};

  bf16x8 af0[4][2], af1[4][2], bfa[2][2], bfb[2][2];

  #define MFMA_QUAD(I0, J0, AF, BF)                                                            \
    __builtin_amdgcn_s_setprio(1);                                                             \
    _Pragma("unroll")                                                                          \
    for (int i = 0; i < 4; i++)                                                                \
      _Pragma("unroll")                                                                        \
      for (int j = 0; j < 2; j++) {                                                            \
        acc[(I0) + i][(J0) + j] = __builtin_amdgcn_mfma_f32_16x16x32_bf16(                     \
            AF[i][0], BF[j][0], acc[(I0) + i][(J0) + j], 0, 0, 0);                             \
        acc[(I0) + i][(J0) + j] = __builtin_amdgcn_mfma_f32_16x16x32_bf16(                     \
            AF[i][1], BF[j][1], acc[(I0) + i][(J0) + j], 0, 0, 0);                             \
      }                                                                                        \
    __builtin_amdgcn_s_setprio(0);

  #define K_ITER(BUF, WC)                                                                      \
  {                                                                                            \
    const bool st = ((WC) + 2 < NT);                                                           \
    const int U = (WC) + 2;                                                                    \
    const char* pA = (const char*)smA[BUF] + rA * 128;                                         \
    const char* pB = (const char*)smB[BUF] + rB * 128;                                         \
    /* issue ALL 24 ds_reads: A0(8), B0(4), B1(4), A1(8) */                                    \
    _Pragma("unroll")                                                                          \
    for (int i = 0; i < 4; i++) {                                                              \
      af0[i][0] = dsr128(pA + i * 2048 + kc0);                                                 \
      af0[i][1] = dsr128(pA + i * 2048 + kc1);                                                 \
    }                                                                                          \
    _Pragma("unroll")                                                                          \
    for (int j = 0; j < 2; j++) {                                                              \
      bfa[j][0] = dsr128(pB + j * 2048 + kc0);                                                 \
      bfa[j][1] = dsr128(pB + j * 2048 + kc1);                                                 \
    }                                                                                          \
    _Pragma("unroll")                                                                          \
    for (int j = 0; j < 2; j++) {                                                              \
      bfb[j][0] = dsr128(pB + (j + 2) * 2048 + kc0);                                           \
      bfb[j][1] = dsr128(pB + (j + 2) * 2048 + kc1);                                           \
    }                                                                                          \
    _Pragma("unroll")                                                                          \
    for (int i = 0; i < 4; i++) {                                                              \
      af1[i][0] = dsr128(pA + (i + 4) * 2048 + kc0);                                           \
      af1[i][1] = dsr128(pA + (i + 4) * 2048 + kc1);                                           \
    }                                                                                          \
    asm volatile("s_waitcnt lgkmcnt(12)");                                                     \
    __builtin_amdgcn_sched_barrier(0);                                                         \
    MFMA_QUAD(0, 0, af0, bfa)                                                                  \
    asm volatile("s_waitcnt lgkmcnt(8)");                                                      \
    __builtin_amdgcn_sched_barrier(0);                                                         \
    MFMA_QUAD(0, 2, af0, bfb)                                                                  \
    asm volatile("s_waitcnt lgkmcnt(0)");                                                      \
    __builtin_amdgcn_sched_barrier(0);                                                         \
    __builtin_amdgcn_s_barrier();   /* all waves finished reading BUF */                       \
    if (st) { STAGE_A(BUF, 0, U); STAGE_A(BUF, 1, U); STAGE_A(BUF, 2, U); STAGE_A(BUF, 3, U);  \
              STAGE_B(BUF, 0, U); STAGE_B(BUF, 1, U); STAGE_B(BUF, 2, U); STAGE_B(BUF, 3, U); }\
    MFMA_QUAD(4, 0, af1, bfa)                                                                  \
    MFMA_QUAD(4, 2, af1, bfb)                                                                  \
    if (st) { asm volatile("s_waitcnt vmcnt(8)"); }                                            \
    else    { asm volatile("s_waitcnt vmcnt(0)"); }                                            \
    __builtin_amdgcn_sched_barrier(0);                                                         \
    __builtin_amdgcn_s_barrier();                                                              \
  }

  for (int W = 0; W < NT; W += 2) {
    K_ITER(0, W)
    K_ITER(1, W + 1)
  }

  #undef K_ITER
  #undef MFMA_QUAD
  #undef STAGE_A
  #undef STAGE_B

  // epilogue
  #pragma unroll
  for (int i = 0; i < 8; i++)
    #pragma unroll
    for (int j = 0; j < 4; j++)
      #pragma unroll
      for (int r = 0; r < 4; r++) {
        const int grow = m0 + wm * 128 + i * 16 + lk * 4 + r;
        const int gcol = n0 + wn * 64 + j * 16 + lr;
        const size_t idx = (size_t)grow * N + gcol;
        const float val = acc[i][j][r];
        if (EPI == 0) {
          const float s = (gcol < ncut) ? scale : 1.0f;
          ((u16*)out)[idx] = f2bf(val * s);
        } else if (EPI == 2) {
          float gv = bf2f(((const u16*)ep)[idx]);
          float sg = gv / (1.f + __expf(-gv));
          ((u16*)out)[idx] = f2bf(sg * val);
        } else {
          unsafeAtomicAdd((float*)out + idx, val);
        }
      }
}

// ---------------- legacy 128x128 GEMM (o-proj) ----------------
// EPI 1: out fp32 = acc + ep_fp32[idx]
template <int EPI>
__global__ __launch_bounds__(256, 2)
void gemm_bt(const u16* __restrict__ A, const u16* __restrict__ B,
             void* out, const void* ep, int M, int N, int K, float scale) {
  __shared__ u16 As[128 * 32];
  __shared__ u16 Bs[128 * 32];
  const int tid = threadIdx.x;
  const int lane = tid & 63;
  const int w = tid >> 6;
  const int wr = w >> 1, wc = w & 1;
  const int nx = gridDim.x;
  const int nwg = nx * gridDim.y;
  const int flat = blockIdx.y * nx + blockIdx.x;
  const int swz = (flat & 7) * (nwg >> 3) + (flat >> 3);
  const int m0 = (swz / nx) * 128;
  const int n0 = (swz % nx) * 128;
  const int lr = lane & 15;
  const int lk = lane >> 4;
  const int srow = lane >> 2;
  const int scol = (lane & 3) * 8;

  const f32x4 zero4 = {0.f, 0.f, 0.f, 0.f};
  f32x4 acc[4][4];
  #pragma unroll
  for (int i = 0; i < 4; i++)
    #pragma unroll
    for (int j = 0; j < 4; j++) acc[i][j] = zero4;

  for (int kt = 0; kt < K; kt += 32) {
    __syncthreads();
    #pragma unroll
    for (int c = 0; c < 2; c++) {
      const int rbase = w * 32 + c * 16;
      gload_lds16(A + (size_t)(m0 + rbase + srow) * K + kt + scol, &As[rbase * 32]);
      gload_lds16(B + (size_t)(n0 + rbase + srow) * K + kt + scol, &Bs[rbase * 32]);
    }
    __syncthreads();
    bf16x8 af[4], bfr[4];
    #pragma unroll
    for (int i = 0; i < 4; i++)
      af[i] = *(const bf16x8*)&As[(wr * 64 + i * 16 + lr) * 32 + lk * 8];
    #pragma unroll
    for (int j = 0; j < 4; j++)
      bfr[j] = *(const bf16x8*)&Bs[(wc * 64 + j * 16 + lr) * 32 + lk * 8];
    #pragma unroll
    for (int i = 0; i < 4; i++)
      #pragma unroll
      for (int j = 0; j < 4; j++)
        acc[i][j] = __builtin_amdgcn_mfma_f32_16x16x32_bf16(af[i], bfr[j], acc[i][j], 0, 0, 0);
  }

  const int r0 = lk * 4;
  #pragma unroll
  for (int i = 0; i < 4; i++) {
    #pragma unroll
    for (int j = 0; j < 4; j++) {
      #pragma unroll
      for (int r = 0; r < 4; r++) {
        const int grow = m0 + wr * 64 + i * 16 + r0 + r;
        const int gcol = n0 + wc * 64 + j * 16 + lr;
        const size_t idx = (size_t)grow * N + gcol;
        const float val = acc[i][j][r];
        if (EPI == 0) {
          ((u16*)out)[idx] = f2bf(val * scale);
        } else if (EPI == 1) {
          ((float*)out)[idx] = ((const float*)ep)[idx] + val;
        } else {
          float gv = bf2f(((const u16*)ep)[idx]);
          float sg = gv / (1.f + __expf(-gv));
          ((u16*)out)[idx] = f2bf(sg * val);
        }
      }
    }
  }
}

// ---------------- V transpose from packed qkv: -> vt[bh=64][d=64][s=2048] ----
__global__ __launch_bounds__(256) void vtrans(const u16* __restrict__ qkv,
                                              u16* __restrict__ vt) {
  __shared__ u16 T[64][72];
  const int t = threadIdx.x;
  const int s0 = blockIdx.x * 64;
  const int h = blockIdx.y;
  const int b = blockIdx.z;
  const int sl = t >> 2, dl = (t & 3) * 16;
  const u16* src = qkv + ((size_t)(b * 2048 + s0 + sl)) * 3072 + 2048 + h * 64 + dl;
  bf16x8 v0 = *(const bf16x8*)src;
  bf16x8 v1 = *(const bf16x8*)(src + 8);
  #pragma unroll
  for (int j = 0; j < 8; j++) T[dl + j][sl] = (u16)v0[j];
  #pragma unroll
  for (int j = 0; j < 8; j++) T[dl + 8 + j][sl] = (u16)v1[j];
  __syncthreads();
  const int dl2 = t >> 2, sl2 = (t & 3) * 16;
  u16* dst = vt + ((size_t)((b * 16 + h) * 64 + dl2)) * 2048 + s0 + sl2;
  *(bf16x8*)dst = *(const bf16x8*)&T[dl2][sl2];
  *(bf16x8*)(dst + 8) = *(const bf16x8*)&T[dl2][sl2 + 8];
}

// ---------------- causal flash attention (packed qkv input) ----------------
__global__ __launch_bounds__(256)
void attn_fwd2(const u16* __restrict__ qkv, const u16* __restrict__ vt,
               u16* __restrict__ o) {
  __shared__ u16 sm[9216];
  u16* const smK = sm;
  u16* const smV = sm + 4096;

  const int tid = threadIdx.x;
  const int lane = tid & 63;
  const int w = tid >> 6;
  const int hi = lane >> 5;
  const int ln = lane & 31;

  const int flat = blockIdx.y * 16 + blockIdx.x;
  const int swz = (flat & 7) * 128 + (flat >> 3);
  const int qt = swz & 15;
  const int bh = swz >> 4;
  const int b = bh >> 4, h = bh & 15;

  const int qbase = qt * 128;
  const int qw0 = qbase + w * 32;
  const int qglob = qw0 + ln;
  const int nkb = qt * 2 + 2;

  bf16x8 qf[4];
  {
    const u16* qp = qkv + ((size_t)(b * 2048 + qw0 + ln)) * 3072 + h * 64 + hi * 8;
    #pragma unroll
    for (int c = 0; c < 4; c++) qf[c] = *(const bf16x8*)(qp + c * 16);
  }

  f32x16 accO[2];
  #pragma unroll
  for (int i = 0; i < 2; i++)
    #pragma unroll
    for (int r = 0; r < 16; r++) accO[i][r] = 0.f;
  float mrun = -1e30f, lsum = 0.f;

  for (int kb = 0; kb < nkb; kb++) {
    const int kbase = kb * 64;
    __syncthreads();
    #pragma unroll
    for (int r = 0; r < 2; r++) {
      const int cb = w * 128 + r * 64;
      const int ci = cb + lane;
      {
        const int key = ci >> 3, gch = (ci & 7) ^ (key & 7);
        const u16* src = qkv + ((size_t)(b * 2048 + kbase + key)) * 3072 + 1024 + h * 64 + gch * 8;
        gload_lds16(src, (char*)smK + cb * 16);
      }
      {
        const int d = ci >> 3, gch = (ci & 7) ^ (d & 7);
        const u16* src = vt + ((size_t)(bh * 64 + d)) * 2048 + kbase + gch * 8;
        gload_lds16(src, (char*)smV + cb * 16);
      }
    }
    __syncthreads();

    if (kbase <= qw0 + 31) {
      f32x16 st[2];
      #pragma unroll
      for (int kt = 0; kt < 2; kt++) {
        #pragma unroll
        for (int r = 0; r < 16; r++) st[kt][r] = 0.f;
        #pragma unroll
        for (int c = 0; c < 4; c++) {
          const int row = kt * 32 + ln;
          const int sch = (c * 2 + hi) ^ (ln & 7);
          bf16x8 kf = *(const bf16x8*)((const char*)smK + row * 128 + sch * 16);
          st[kt] = __builtin_amdgcn_mfma_f32_32x32x16_bf16(kf, qf[c], st[kt], 0, 0, 0);
        }
      }
      if (kbase + 63 > qw0) {
        #pragma unroll
        for (int kt = 0; kt < 2; kt++)
          #pragma unroll
          for (int r = 0; r < 16; r++) {
            const int kk = kbase + kt * 32 + (r & 3) + 8 * (r >> 2) + 4 * hi;
            if (kk > qglob) st[kt][r] = -1e30f;
          }
      }
      float pm = st[0][0];
      #pragma unroll
      for (int kt = 0; kt < 2; kt++)
        #pragma unroll
        for (int r = 0; r < 16; r++) pm = fmaxf(pm, st[kt][r]);
      pm = fmaxf(pm, __shfl_xor(pm, 32));
      const float mnew = fmaxf(mrun, pm);
      const float alpha = __expf(mrun - mnew);
      float ps = 0.f;
      #pragma unroll
      for (int kt = 0; kt < 2; kt++)
        #pragma unroll
        for (int r = 0; r < 16; r++) {
          const float p = __expf(st[kt][r] - mnew);
          st[kt][r] = p;
          ps += p;
        }
      ps += __shfl_xor(ps, 32);
      lsum = lsum * alpha + ps;
      mrun = mnew;
      accO[0] *= alpha;
      accO[1] *= alpha;

      #pragma unroll
      for (int kt = 0; kt < 2; kt++) {
        u32 pw[8], px[8];
        #pragma unroll
        for (int i = 0; i < 8; i++) pw[i] = pack2(st[kt][2 * i], st[kt][2 * i + 1]);
        #pragma unroll
        for (int i = 0; i < 8; i++) px[i] = (u32)__shfl_xor((int)pw[i], 32);
        union { u32 wd[4]; bf16x8 v; } f0, f1;
        f0.wd[0] = hi ? px[2] : pw[0];
        f0.wd[1] = hi ? px[3] : pw[1];
        f0.wd[2] = hi ? pw[2] : px[0];
        f0.wd[3] = hi ? pw[3] : px[1];
        f1.wd[0] = hi ? px[6] : pw[4];
        f1.wd[1] = hi ? px[7] : pw[5];
        f1.wd[2] = hi ? pw[6] : px[4];
        f1.wd[3] = hi ? pw[7] : px[5];
        #pragma unroll
        for (int d0 = 0; d0 < 2; d0++) {
          #pragma unroll
          for (int kc = 0; kc < 2; kc++) {
            const int drow = d0 * 32 + ln;
            const int sch = (kt * 4 + kc * 2 + hi) ^ (ln & 7);
            bf16x8 vf = *(const bf16x8*)((const char*)smV + drow * 128 + sch * 16);
            accO[d0] = __builtin_amdgcn_mfma_f32_32x32x16_bf16(vf, kc ? f1.v : f0.v,
                                                               accO[d0], 0, 0, 0);
          }
        }
      }
    }
  }

  __syncthreads();
  const float inv = 1.0f / lsum;
  #pragma unroll
  for (int d0 = 0; d0 < 2; d0++)
    #pragma unroll
    for (int r = 0; r < 16; r++) {
      const int d = d0 * 32 + (r & 3) + 8 * (r >> 2) + 4 * hi;
      sm[(w * 32 + ln) * 72 + d] = f2bf(accO[d0][r] * inv);
    }
  __syncthreads();
  const int ql = tid >> 1, dh = (tid & 1) * 32;
  const u16* srcp = &sm[ql * 72 + dh];
  u16* dst = o + ((size_t)(b * 2048 + qbase + ql)) * 1024 + h * 64 + dh;
  #pragma unroll
  for (int j = 0; j < 4; j++)
    *(bf16x8*)(dst + j * 8) = *(const bf16x8*)(srcp + j * 8);
}

// ---------------- host ----------------
extern "C" void kernel_launch(void* const* d_in, const int* in_sizes, int n_in,
                              void* d_out, int out_size, void* d_ws, size_t ws_size,
                              hipStream_t stream) {
  const float* x      = (const float*)d_in[0];
  const float* W_q    = (const float*)d_in[1];
  const float* W_k    = (const float*)d_in[2];
  const float* W_v    = (const float*)d_in[3];
  const float* W_o    = (const float*)d_in[4];
  const float* gamma1 = (const float*)d_in[5];
  const float* gamma2 = (const float*)d_in[6];
  const float* W1     = (const float*)d_in[7];
  const float* W2     = (const float*)d_in[8];
  const float* W3     = (const float*)d_in[9];

  char* ws = (char*)d_ws;
  const size_t MB = 1ull << 20;
  u16* qkvw  = (u16*)(ws + 0 * MB);    // Wq|Wk|Wv rows concat [3072][1024]
  u16* Wo_b  = (u16*)(ws + 6 * MB);
  u16* W1_b  = (u16*)(ws + 8 * MB);
  u16* W3_b  = (u16*)(ws + 16 * MB);
  u16* W2_b  = (u16*)(ws + 24 * MB);
  u16* xn    = (u16*)(ws + 32 * MB);   // 16 MB
  u16* qkvb  = (u16*)(ws + 48 * MB);   // [8192][3072] = 48 MB -> 48..96
  u16* attnb = (u16*)(ws + 96 * MB);   // 16 MB
  u16* vtb   = (u16*)(ws + 112 * MB);  // 16 MB (dead after attn)
  u16* gbuf  = (u16*)(ws + 112 * MB);  // 64 MB -> 112..176 (after attn)
  u16* hbuf  = (u16*)(ws + 48 * MB);   // 64 MB, reuses qkvb+attnb (dead)
  float* x1  = (float*)d_out;

  castw<<<1024, 256, 0, stream>>>(W_q, qkvw, 262144);
  castw<<<1024, 256, 0, stream>>>(W_k, qkvw + 1024 * 1024, 262144);
  castw<<<1024, 256, 0, stream>>>(W_v, qkvw + 2048 * 1024, 262144);
  castw<<<1024, 256, 0, stream>>>(W_o, Wo_b, 262144);
  castw<<<4096, 256, 0, stream>>>(W1, W1_b, 1048576);
  castw<<<4096, 256, 0, stream>>>(W3, W3_b, 1048576);
  castw<<<4096, 256, 0, stream>>>(W2, W2_b, 1048576);

  rmsnorm_k<<<8192, 256, 0, stream>>>(x, gamma1, xn);
  gemm256<0><<<dim3(12, 32), 512, 0, stream>>>(xn, qkvw, qkvb, nullptr,
                                               8192, 3072, 1024, 1024, 0.125f, 1024);
  vtrans<<<dim3(32, 16, 4), 256, 0, stream>>>(qkvb, vtb);
  attn_fwd2<<<dim3(16, 64), 256, 0, stream>>>(qkvb, vtb, attnb);
  gemm_bt<1><<<dim3(8, 64), 256, 0, stream>>>(attnb, Wo_b, x1, x, 8192, 1024, 1024, 1.0f);

  rmsnorm_k<<<8192, 256, 0, stream>>>(x1, gamma2, xn);
  gemm256<0><<<dim3(16, 32), 512, 0, stream>>>(xn, W1_b, gbuf, nullptr,
                                               8192, 4096, 1024, 1024, 1.0f, 0);
  gemm256<2><<<dim3(16, 32), 512, 0, stream>>>(xn, W3_b, hbuf, gbuf,
                                               8192, 4096, 1024, 1024, 1.0f, 0);
  // down-proj: split-K=2, fp32 atomic accumulate into d_out (holds x1)
  gemm256<3><<<dim3(4, 32, 2), 512, 0, stream>>>(hbuf, W2_b, (float*)d_out, nullptr,
                                                 8192, 1024, 2048, 4096, 1.0f, 0);
}

// Round 7
// 551.089 us; speedup vs baseline: 1.0237x; 1.0177x over previous
//
#include <hip/hip_runtime.h>
#include <cstdint>
#include <cstddef>

typedef unsigned short u16;
typedef unsigned int u32;
typedef short bf16x8 __attribute__((ext_vector_type(8)));
typedef float f32x4 __attribute__((ext_vector_type(4)));
typedef float f32x16 __attribute__((ext_vector_type(16)));
typedef u16 u16x4 __attribute__((ext_vector_type(4)));

__device__ __forceinline__ u16 f2bf(float f) {
  u32 u = __float_as_uint(f);
  return (u16)((u + 0x7FFFu + ((u >> 16) & 1u)) >> 16);
}
__device__ __forceinline__ float bf2f(u16 h) {
  return __uint_as_float(((u32)h) << 16);
}
__device__ __forceinline__ u32 pack2(float a, float b) {
  return (u32)f2bf(a) | ((u32)f2bf(b) << 16);
}

__device__ __forceinline__ void gload_lds16(const void* g, void* l) {
  __builtin_amdgcn_global_load_lds((const __attribute__((address_space(1))) u32*)g,
                                   (__attribute__((address_space(3))) u32*)l, 16, 0, 0);
}

typedef const __attribute__((address_space(3))) u16* lds_cp;
__device__ __forceinline__ bf16x8 dsr128(const void* p) {
  bf16x8 d;
  asm volatile("ds_read_b128 %0, %1" : "=&v"(d) : "v"((lds_cp)p));
  return d;
}

// ---------------- weight cast fp32 -> bf16 ----------------
__global__ __launch_bounds__(256) void castw(const float* __restrict__ src,
                                             u16* __restrict__ dst, int n4) {
  int i = blockIdx.x * 256 + threadIdx.x;
  if (i < n4) {
    float4 v = ((const float4*)src)[i];
    u16x4 r;
    r.x = f2bf(v.x); r.y = f2bf(v.y); r.z = f2bf(v.z); r.w = f2bf(v.w);
    ((u16x4*)dst)[i] = r;
  }
}

// ---------------- RMSNorm: fp32 [rows,1024] -> bf16 ----------------
__global__ __launch_bounds__(256) void rmsnorm_k(const float* __restrict__ x,
                                                 const float* __restrict__ gamma,
                                                 u16* __restrict__ o) {
  const int row = blockIdx.x;
  const int t = threadIdx.x;
  float4 v = ((const float4*)(x + (size_t)row * 1024))[t];
  float ss = v.x * v.x + v.y * v.y + v.z * v.z + v.w * v.w;
  #pragma unroll
  for (int m = 1; m < 64; m <<= 1) ss += __shfl_xor(ss, m);
  __shared__ float wsum[4];
  if ((t & 63) == 0) wsum[t >> 6] = ss;
  __syncthreads();
  float tot = wsum[0] + wsum[1] + wsum[2] + wsum[3];
  float inv = rsqrtf(tot * (1.0f / 1024.0f) + 1e-5f);
  float4 g = ((const float4*)gamma)[t];
  u16x4 r;
  r.x = f2bf(v.x * inv * g.x);
  r.y = f2bf(v.y * inv * g.y);
  r.z = f2bf(v.z * inv * g.z);
  r.w = f2bf(v.w * inv * g.w);
  ((u16x4*)(o + (size_t)row * 1024))[t] = r;
}

// ========== 256xBN minimum-2-phase GEMM: C[M,N] = A[M,K] * B[N,K]^T =========
// NJ = BN/64 (4 or 2). Per K-tile: prefetch next tile FIRST (global_load_lds),
// then ds_reads of current, lgkmcnt(0), MFMA; ONE vmcnt(0)+barrier per tile
// (prefetch drains against the whole read+MFMA phase).  [T3 minimum recipe]
// EPI 0: bf16 = acc * (n0<ncut?scale:1)  (LDS-bounced coalesced stores)
// EPI 2: bf16 = silu(ep[idx]) * acc      (LDS-bounced, vectorized ep reads)
// EPI 3: fp32 unsafeAtomicAdd(out+idx, acc)  (split-K via blockIdx.z)
template <int EPI, int NJ>
__global__ __launch_bounds__(512, 2)
void gemm256(const u16* __restrict__ A, const u16* __restrict__ B,
             void* out, const void* ep, int M, int N, int KLOOP, int KS,
             float scale, int ncut) {
  constexpr int BN = NJ * 64;
  __shared__ u16 sm[2][16384 + NJ * 4096];   // [buf][A 256x64 | B BNx64]

  const int tid = threadIdx.x;
  const int lane = tid & 63;
  const int w = tid >> 6;
  const int wm = w >> 2, wn = w & 3;
  const int lr = lane & 15, lk = lane >> 4;

  A += (size_t)blockIdx.z * KLOOP;
  B += (size_t)blockIdx.z * KLOOP;

  // bijective XCD swizzle + 2D chunking (8 m-rows per super-row)
  const int nx = gridDim.x;
  const int nwg = nx * gridDim.y;
  const int flat = blockIdx.y * nx + blockIdx.x;
  const int qq = nwg >> 3, rr = nwg & 7;
  const int xcd = flat & 7, off = flat >> 3;
  const int swz = (xcd < rr ? xcd * (qq + 1) : rr * (qq + 1) + (xcd - rr) * qq) + off;
  const int sr = nx * 8;
  const int g8 = swz / sr, rem = swz % sr;
  const int m0 = (g8 * 8 + (rem & 7)) * 256;
  const int n0 = (rem >> 3) * BN;

  const int srow = w * 8 + (lane >> 3);
  const int sch8 = (((lane & 7) ^ ((lane >> 3) & 7)) << 3);

  const int rA = wm * 128 + lr;
  const int rB = wn * (NJ * 16) + lr;
  const int kc0 = (lk ^ (lr & 7)) << 4;
  const int kc1 = kc0 ^ 64;

  const int NT = KLOOP >> 6;

  #define STAGE_A(nb, q, U) gload_lds16(A + (size_t)(m0 + (q) * 64 + srow) * KS + ((U) << 6) + sch8, \
                                        (char*)sm[nb] + (q) * 8192 + w * 1024)
  #define STAGE_B(nb, q, U) gload_lds16(B + (size_t)(n0 + (q) * 64 + srow) * KS + ((U) << 6) + sch8, \
                                        (char*)sm[nb] + 32768 + (q) * 8192 + w * 1024)

  // prologue: stage tile 0 into buf0, full drain, barrier
  #pragma unroll
  for (int q = 0; q < 4; q++) STAGE_A(0, q, 0);
  #pragma unroll
  for (int q = 0; q < NJ; q++) STAGE_B(0, q, 0);
  asm volatile("s_waitcnt vmcnt(0)");
  asm volatile("s_waitcnt lgkmcnt(0)");
  __builtin_amdgcn_sched_barrier(0);
  __builtin_amdgcn_s_barrier();

  f32x4 acc[8][NJ];
  #pragma unroll
  for (int i = 0; i < 8; i++)
    #pragma unroll
    for (int j = 0; j < NJ; j++) acc[i][j] = (f32x4){0.f, 0.f, 0.f, 0.f};

  bf16x8 af[4], bfr[NJ][2];

  for (int W = 0; W < NT; ++W) {
    const int buf = W & 1;
    const char* pA = (const char*)sm[buf] + rA * 128;
    const char* pB = (const char*)sm[buf] + 32768 + rB * 128;

    // 1) prefetch next K-tile into the other buffer (VMEM issue only)
    if (W + 1 < NT) {
      const int nb = buf ^ 1, U = W + 1;
      STAGE_A(nb, 0, U); STAGE_A(nb, 1, U); STAGE_A(nb, 2, U); STAGE_A(nb, 3, U);
      #pragma unroll
      for (int q = 0; q < NJ; q++) STAGE_B(nb, q, U);
    }
    __builtin_amdgcn_sched_barrier(0);

    // 2) read B (all) + A(ih0); compute quads (ih0, *)
    #pragma unroll
    for (int j = 0; j < NJ; j++) {
      bfr[j][0] = dsr128(pB + j * 2048 + kc0);
      bfr[j][1] = dsr128(pB + j * 2048 + kc1);
    }
    #pragma unroll
    for (int i = 0; i < 4; i++) {
      af[i] = dsr128(pA + i * 2048 + kc0);
    }
    bf16x8 af1_[4];
    #pragma unroll
    for (int i = 0; i < 4; i++) af1_[i] = dsr128(pA + i * 2048 + kc1);
    asm volatile("s_waitcnt lgkmcnt(0)");
    __builtin_amdgcn_sched_barrier(0);
    __builtin_amdgcn_s_setprio(1);
    #pragma unroll
    for (int i = 0; i < 4; i++)
      #pragma unroll
      for (int j = 0; j < NJ; j++) {
        acc[i][j] = __builtin_amdgcn_mfma_f32_16x16x32_bf16(af[i], bfr[j][0], acc[i][j], 0, 0, 0);
        acc[i][j] = __builtin_amdgcn_mfma_f32_16x16x32_bf16(af1_[i], bfr[j][1], acc[i][j], 0, 0, 0);
      }
    __builtin_amdgcn_s_setprio(0);

    // 3) read A(ih1); compute quads (ih1, *)
    #pragma unroll
    for (int i = 0; i < 4; i++) {
      af[i] = dsr128(pA + (i + 4) * 2048 + kc0);
      af1_[i] = dsr128(pA + (i + 4) * 2048 + kc1);
    }
    asm volatile("s_waitcnt lgkmcnt(0)");
    __builtin_amdgcn_sched_barrier(0);
    __builtin_amdgcn_s_setprio(1);
    #pragma unroll
    for (int i = 0; i < 4; i++)
      #pragma unroll
      for (int j = 0; j < NJ; j++) {
        acc[i + 4][j] = __builtin_amdgcn_mfma_f32_16x16x32_bf16(af[i], bfr[j][0], acc[i + 4][j], 0, 0, 0);
        acc[i + 4][j] = __builtin_amdgcn_mfma_f32_16x16x32_bf16(af1_[i], bfr[j][1], acc[i + 4][j], 0, 0, 0);
      }
    __builtin_amdgcn_s_setprio(0);

    // 4) prefetch landed + all waves done reading buf
    asm volatile("s_waitcnt vmcnt(0)");
    __builtin_amdgcn_sched_barrier(0);
    __builtin_amdgcn_s_barrier();
  }

  #undef STAGE_A
  #undef STAGE_B

  if constexpr (EPI == 3) {
    // scatter fp32 atomics (split-K accumulate)
    #pragma unroll
    for (int i = 0; i < 8; i++)
      #pragma unroll
      for (int j = 0; j < NJ; j++)
        #pragma unroll
        for (int r = 0; r < 4; r++) {
          const int grow = m0 + wm * 128 + i * 16 + lk * 4 + r;
          const int gcol = n0 + wn * (NJ * 16) + j * 16 + lr;
          unsafeAtomicAdd((float*)out + (size_t)grow * N + gcol, acc[i][j][r]);
        }
  } else {
    // LDS-bounce: write acc (bf16, row-swizzled) into sm as C[256][BN]
    const float s = (EPI == 0 && n0 < ncut) ? scale : 1.0f;
    u16* const smC = (u16*)sm;
    #pragma unroll
    for (int i = 0; i < 8; i++)
      #pragma unroll
      for (int j = 0; j < NJ; j++)
        #pragma unroll
        for (int r = 0; r < 4; r++) {
          const int row = wm * 128 + i * 16 + lk * 4 + r;
          const int col = wn * (NJ * 16) + j * 16 + lr;
          smC[row * BN + (col ^ ((row & 7) << 3))] = f2bf(acc[i][j][r] * s);
        }
    __syncthreads();
    // coalesced store: 16B/lane contiguous
    constexpr int CPR = BN / 8;              // 8-elem chunks per row
    constexpr int ITER = (256 * CPR) / 512;
    #pragma unroll
    for (int it = 0; it < ITER; it++) {
      const int fl = it * 512 + tid;
      const int row = fl / CPR;
      const int col = (fl % CPR) * 8;
      const int sw = (row & 7) << 3;
      bf16x8 cv = *(const bf16x8*)&smC[row * BN + (col ^ sw)];
      const size_t gidx = (size_t)(m0 + row) * N + n0 + col;
      if (EPI == 0) {
        *(bf16x8*)((u16*)out + gidx) = cv;
      } else {
        bf16x8 gv = *(const bf16x8*)((const u16*)ep + gidx);
        bf16x8 ov;
        #pragma unroll
        for (int k = 0; k < 8; k++) {
          float g = bf2f((u16)gv[k]);
          float sg = g / (1.f + __expf(-g));
          ov[k] = (short)f2bf(sg * bf2f((u16)cv[k]));
        }
        *(bf16x8*)((u16*)out + gidx) = ov;
      }
    }
  }
}

// ---------------- legacy 128x128 GEMM (o-proj) ----------------
// EPI 1: out fp32 = acc + ep_fp32[idx]
template <int EPI>
__global__ __launch_bounds__(256, 2)
void gemm_bt(const u16* __restrict__ A, const u16* __restrict__ B,
             void* out, const void* ep, int M, int N, int K, float scale) {
  __shared__ u16 As[128 * 32];
  __shared__ u16 Bs[128 * 32];
  const int tid = threadIdx.x;
  const int lane = tid & 63;
  const int w = tid >> 6;
  const int wr = w >> 1, wc = w & 1;
  const int nx = gridDim.x;
  const int nwg = nx * gridDim.y;
  const int flat = blockIdx.y * nx + blockIdx.x;
  const int swz = (flat & 7) * (nwg >> 3) + (flat >> 3);
  const int m0 = (swz / nx) * 128;
  const int n0 = (swz % nx) * 128;
  const int lr = lane & 15;
  const int lk = lane >> 4;
  const int srow = lane >> 2;
  const int scol = (lane & 3) * 8;

  const f32x4 zero4 = {0.f, 0.f, 0.f, 0.f};
  f32x4 acc[4][4];
  #pragma unroll
  for (int i = 0; i < 4; i++)
    #pragma unroll
    for (int j = 0; j < 4; j++) acc[i][j] = zero4;

  for (int kt = 0; kt < K; kt += 32) {
    __syncthreads();
    #pragma unroll
    for (int c = 0; c < 2; c++) {
      const int rbase = w * 32 + c * 16;
      gload_lds16(A + (size_t)(m0 + rbase + srow) * K + kt + scol, &As[rbase * 32]);
      gload_lds16(B + (size_t)(n0 + rbase + srow) * K + kt + scol, &Bs[rbase * 32]);
    }
    __syncthreads();
    bf16x8 af[4], bfr[4];
    #pragma unroll
    for (int i = 0; i < 4; i++)
      af[i] = *(const bf16x8*)&As[(wr * 64 + i * 16 + lr) * 32 + lk * 8];
    #pragma unroll
    for (int j = 0; j < 4; j++)
      bfr[j] = *(const bf16x8*)&Bs[(wc * 64 + j * 16 + lr) * 32 + lk * 8];
    #pragma unroll
    for (int i = 0; i < 4; i++)
      #pragma unroll
      for (int j = 0; j < 4; j++)
        acc[i][j] = __builtin_amdgcn_mfma_f32_16x16x32_bf16(af[i], bfr[j], acc[i][j], 0, 0, 0);
  }

  const int r0 = lk * 4;
  #pragma unroll
  for (int i = 0; i < 4; i++) {
    #pragma unroll
    for (int j = 0; j < 4; j++) {
      #pragma unroll
      for (int r = 0; r < 4; r++) {
        const int grow = m0 + wr * 64 + i * 16 + r0 + r;
        const int gcol = n0 + wc * 64 + j * 16 + lr;
        const size_t idx = (size_t)grow * N + gcol;
        const float val = acc[i][j][r];
        if (EPI == 0) {
          ((u16*)out)[idx] = f2bf(val * scale);
        } else if (EPI == 1) {
          ((float*)out)[idx] = ((const float*)ep)[idx] + val;
        } else {
          float gv = bf2f(((const u16*)ep)[idx]);
          float sg = gv / (1.f + __expf(-gv));
          ((u16*)out)[idx] = f2bf(sg * val);
        }
      }
    }
  }
}

// ---------------- V transpose from packed qkv: -> vt[bh=64][d=64][s=2048] ----
__global__ __launch_bounds__(256) void vtrans(const u16* __restrict__ qkv,
                                              u16* __restrict__ vt) {
  __shared__ u16 T[64][72];
  const int t = threadIdx.x;
  const int s0 = blockIdx.x * 64;
  const int h = blockIdx.y;
  const int b = blockIdx.z;
  const int sl = t >> 2, dl = (t & 3) * 16;
  const u16* src = qkv + ((size_t)(b * 2048 + s0 + sl)) * 3072 + 2048 + h * 64 + dl;
  bf16x8 v0 = *(const bf16x8*)src;
  bf16x8 v1 = *(const bf16x8*)(src + 8);
  #pragma unroll
  for (int j = 0; j < 8; j++) T[dl + j][sl] = (u16)v0[j];
  #pragma unroll
  for (int j = 0; j < 8; j++) T[dl + 8 + j][sl] = (u16)v1[j];
  __syncthreads();
  const int dl2 = t >> 2, sl2 = (t & 3) * 16;
  u16* dst = vt + ((size_t)((b * 16 + h) * 64 + dl2)) * 2048 + s0 + sl2;
  *(bf16x8*)dst = *(const bf16x8*)&T[dl2][sl2];
  *(bf16x8*)(dst + 8) = *(const bf16x8*)&T[dl2][sl2 + 8];
}

// ---------------- causal flash attention (packed qkv input) ----------------
__global__ __launch_bounds__(256)
void attn_fwd2(const u16* __restrict__ qkv, const u16* __restrict__ vt,
               u16* __restrict__ o) {
  __shared__ u16 sm[9216];
  u16* const smK = sm;
  u16* const smV = sm + 4096;

  const int tid = threadIdx.x;
  const int lane = tid & 63;
  const int w = tid >> 6;
  const int hi = lane >> 5;
  const int ln = lane & 31;

  const int flat = blockIdx.y * 16 + blockIdx.x;
  const int swz = (flat & 7) * 128 + (flat >> 3);
  const int qt = swz & 15;
  const int bh = swz >> 4;
  const int b = bh >> 4, h = bh & 15;

  const int qbase = qt * 128;
  const int qw0 = qbase + w * 32;
  const int qglob = qw0 + ln;
  const int nkb = qt * 2 + 2;

  bf16x8 qf[4];
  {
    const u16* qp = qkv + ((size_t)(b * 2048 + qw0 + ln)) * 3072 + h * 64 + hi * 8;
    #pragma unroll
    for (int c = 0; c < 4; c++) qf[c] = *(const bf16x8*)(qp + c * 16);
  }

  f32x16 accO[2];
  #pragma unroll
  for (int i = 0; i < 2; i++)
    #pragma unroll
    for (int r = 0; r < 16; r++) accO[i][r] = 0.f;
  float mrun = -1e30f, lsum = 0.f;

  for (int kb = 0; kb < nkb; kb++) {
    const int kbase = kb * 64;
    __syncthreads();
    #pragma unroll
    for (int r = 0; r < 2; r++) {
      const int cb = w * 128 + r * 64;
      const int ci = cb + lane;
      {
        const int key = ci >> 3, gch = (ci & 7) ^ (key & 7);
        const u16* src = qkv + ((size_t)(b * 2048 + kbase + key)) * 3072 + 1024 + h * 64 + gch * 8;
        gload_lds16(src, (char*)smK + cb * 16);
      }
      {
        const int d = ci >> 3, gch = (ci & 7) ^ (d & 7);
        const u16* src = vt + ((size_t)(bh * 64 + d)) * 2048 + kbase + gch * 8;
        gload_lds16(src, (char*)smV + cb * 16);
      }
    }
    __syncthreads();

    if (kbase <= qw0 + 31) {
      f32x16 st[2];
      #pragma unroll
      for (int kt = 0; kt < 2; kt++) {
        #pragma unroll
        for (int r = 0; r < 16; r++) st[kt][r] = 0.f;
        #pragma unroll
        for (int c = 0; c < 4; c++) {
          const int row = kt * 32 + ln;
          const int sch = (c * 2 + hi) ^ (ln & 7);
          bf16x8 kf = *(const bf16x8*)((const char*)smK + row * 128 + sch * 16);
          st[kt] = __builtin_amdgcn_mfma_f32_32x32x16_bf16(kf, qf[c], st[kt], 0, 0, 0);
        }
      }
      if (kbase + 63 > qw0) {
        #pragma unroll
        for (int kt = 0; kt < 2; kt++)
          #pragma unroll
          for (int r = 0; r < 16; r++) {
            const int kk = kbase + kt * 32 + (r & 3) + 8 * (r >> 2) + 4 * hi;
            if (kk > qglob) st[kt][r] = -1e30f;
          }
      }
      float pm = st[0][0];
      #pragma unroll
      for (int kt = 0; kt < 2; kt++)
        #pragma unroll
        for (int r = 0; r < 16; r++) pm = fmaxf(pm, st[kt][r]);
      pm = fmaxf(pm, __shfl_xor(pm, 32));
      const float mnew = fmaxf(mrun, pm);
      const float alpha = __expf(mrun - mnew);
      float ps = 0.f;
      #pragma unroll
      for (int kt = 0; kt < 2; kt++)
        #pragma unroll
        for (int r = 0; r < 16; r++) {
          const float p = __expf(st[kt][r] - mnew);
          st[kt][r] = p;
          ps += p;
        }
      ps += __shfl_xor(ps, 32);
      lsum = lsum * alpha + ps;
      mrun = mnew;
      accO[0] *= alpha;
      accO[1] *= alpha;

      #pragma unroll
      for (int kt = 0; kt < 2; kt++) {
        u32 pw[8], px[8];
        #pragma unroll
        for (int i = 0; i < 8; i++) pw[i] = pack2(st[kt][2 * i], st[kt][2 * i + 1]);
        #pragma unroll
        for (int i = 0; i < 8; i++) px[i] = (u32)__shfl_xor((int)pw[i], 32);
        union { u32 wd[4]; bf16x8 v; } f0, f1;
        f0.wd[0] = hi ? px[2] : pw[0];
        f0.wd[1] = hi ? px[3] : pw[1];
        f0.wd[2] = hi ? pw[2] : px[0];
        f0.wd[3] = hi ? pw[3] : px[1];
        f1.wd[0] = hi ? px[6] : pw[4];
        f1.wd[1] = hi ? px[7] : pw[5];
        f1.wd[2] = hi ? pw[6] : px[4];
        f1.wd[3] = hi ? pw[7] : px[5];
        #pragma unroll
        for (int d0 = 0; d0 < 2; d0++) {
          #pragma unroll
          for (int kc = 0; kc < 2; kc++) {
            const int drow = d0 * 32 + ln;
            const int sch = (kt * 4 + kc * 2 + hi) ^ (ln & 7);
            bf16x8 vf = *(const bf16x8*)((const char*)smV + drow * 128 + sch * 16);
            accO[d0] = __builtin_amdgcn_mfma_f32_32x32x16_bf16(vf, kc ? f1.v : f0.v,
                                                               accO[d0], 0, 0, 0);
          }
        }
      }
    }
  }

  __syncthreads();
  const float inv = 1.0f / lsum;
  #pragma unroll
  for (int d0 = 0; d0 < 2; d0++)
    #pragma unroll
    for (int r = 0; r < 16; r++) {
      const int d = d0 * 32 + (r & 3) + 8 * (r >> 2) + 4 * hi;
      sm[(w * 32 + ln) * 72 + d] = f2bf(accO[d0][r] * inv);
    }
  __syncthreads();
  const int ql = tid >> 1, dh = (tid & 1) * 32;
  const u16* srcp = &sm[ql * 72 + dh];
  u16* dst = o + ((size_t)(b * 2048 + qbase + ql)) * 1024 + h * 64 + dh;
  #pragma unroll
  for (int j = 0; j < 4; j++)
    *(bf16x8*)(dst + j * 8) = *(const bf16x8*)(srcp + j * 8);
}

// ---------------- host ----------------
extern "C" void kernel_launch(void* const* d_in, const int* in_sizes, int n_in,
                              void* d_out, int out_size, void* d_ws, size_t ws_size,
                              hipStream_t stream) {
  const float* x      = (const float*)d_in[0];
  const float* W_q    = (const float*)d_in[1];
  const float* W_k    = (const float*)d_in[2];
  const float* W_v    = (const float*)d_in[3];
  const float* W_o    = (const float*)d_in[4];
  const float* gamma1 = (const float*)d_in[5];
  const float* gamma2 = (const float*)d_in[6];
  const float* W1     = (const float*)d_in[7];
  const float* W2     = (const float*)d_in[8];
  const float* W3     = (const float*)d_in[9];

  char* ws = (char*)d_ws;
  const size_t MB = 1ull << 20;
  u16* qkvw  = (u16*)(ws + 0 * MB);    // Wq|Wk|Wv rows concat [3072][1024]
  u16* Wo_b  = (u16*)(ws + 6 * MB);
  u16* W1_b  = (u16*)(ws + 8 * MB);
  u16* W3_b  = (u16*)(ws + 16 * MB);
  u16* W2_b  = (u16*)(ws + 24 * MB);
  u16* xn    = (u16*)(ws + 32 * MB);   // 16 MB
  u16* qkvb  = (u16*)(ws + 48 * MB);   // [8192][3072] = 48 MB -> 48..96
  u16* attnb = (u16*)(ws + 96 * MB);   // 16 MB
  u16* vtb   = (u16*)(ws + 112 * MB);  // 16 MB (dead after attn)
  u16* gbuf  = (u16*)(ws + 112 * MB);  // 64 MB -> 112..176 (after attn)
  u16* hbuf  = (u16*)(ws + 48 * MB);   // 64 MB, reuses qkvb+attnb (dead)
  float* x1  = (float*)d_out;

  castw<<<1024, 256, 0, stream>>>(W_q, qkvw, 262144);
  castw<<<1024, 256, 0, stream>>>(W_k, qkvw + 1024 * 1024, 262144);
  castw<<<1024, 256, 0, stream>>>(W_v, qkvw + 2048 * 1024, 262144);
  castw<<<1024, 256, 0, stream>>>(W_o, Wo_b, 262144);
  castw<<<4096, 256, 0, stream>>>(W1, W1_b, 1048576);
  castw<<<4096, 256, 0, stream>>>(W3, W3_b, 1048576);
  castw<<<4096, 256, 0, stream>>>(W2, W2_b, 1048576);

  rmsnorm_k<<<8192, 256, 0, stream>>>(x, gamma1, xn);
  // QKV: BN=128 -> 24x32 = 768 wg (3/CU, even)
  gemm256<0, 2><<<dim3(24, 32), 512, 0, stream>>>(xn, qkvw, qkvb, nullptr,
                                                  8192, 3072, 1024, 1024, 0.125f, 1024);
  vtrans<<<dim3(32, 16, 4), 256, 0, stream>>>(qkvb, vtb);
  attn_fwd2<<<dim3(16, 64), 256, 0, stream>>>(qkvb, vtb, attnb);
  gemm_bt<1><<<dim3(8, 64), 256, 0, stream>>>(attnb, Wo_b, x1, x, 8192, 1024, 1024, 1.0f);

  rmsnorm_k<<<8192, 256, 0, stream>>>(x1, gamma2, xn);
  gemm256<0, 4><<<dim3(16, 32), 512, 0, stream>>>(xn, W1_b, gbuf, nullptr,
                                                  8192, 4096, 1024, 1024, 1.0f, 0);
  gemm256<2, 4><<<dim3(16, 32), 512, 0, stream>>>(xn, W3_b, hbuf, gbuf,
                                                  8192, 4096, 1024, 1024, 1.0f, 0);
  // down-proj: BN=128, split-K=2 -> 8x32x2 = 512 wg (2/CU), atomic into d_out
  gemm256<3, 2><<<dim3(8, 32, 2), 512, 0, stream>>>(hbuf, W2_b, (float*)d_out, nullptr,
                                                    8192, 1024, 2048, 4096, 1.0f, 0);
}

// Round 8
// 521.959 us; speedup vs baseline: 1.0808x; 1.0558x over previous
//
#include <hip/hip_runtime.h>
#include <cstdint>
#include <cstddef>

typedef unsigned short u16;
typedef unsigned int u32;
typedef short bf16x8 __attribute__((ext_vector_type(8)));
typedef float f32x4 __attribute__((ext_vector_type(4)));
typedef float f32x16 __attribute__((ext_vector_type(16)));
typedef u16 u16x4 __attribute__((ext_vector_type(4)));

__device__ __forceinline__ u16 f2bf(float f) {
  u32 u = __float_as_uint(f);
  return (u16)((u + 0x7FFFu + ((u >> 16) & 1u)) >> 16);
}
__device__ __forceinline__ float bf2f(u16 h) {
  return __uint_as_float(((u32)h) << 16);
}
__device__ __forceinline__ u32 pack2(float a, float b) {
  return (u32)f2bf(a) | ((u32)f2bf(b) << 16);
}

__device__ __forceinline__ void gload_lds16(const void* g, void* l) {
  __builtin_amdgcn_global_load_lds((const __attribute__((address_space(1))) u32*)g,
                                   (__attribute__((address_space(3))) u32*)l, 16, 0, 0);
}

// ---------------- weight cast fp32 -> bf16 ----------------
__global__ __launch_bounds__(256) void castw(const float* __restrict__ src,
                                             u16* __restrict__ dst, int n4) {
  int i = blockIdx.x * 256 + threadIdx.x;
  if (i < n4) {
    float4 v = ((const float4*)src)[i];
    u16x4 r;
    r.x = f2bf(v.x); r.y = f2bf(v.y); r.z = f2bf(v.z); r.w = f2bf(v.w);
    ((u16x4*)dst)[i] = r;
  }
}

// ---------------- RMSNorm: fp32 [rows,1024] -> bf16 ----------------
__global__ __launch_bounds__(256) void rmsnorm_k(const float* __restrict__ x,
                                                 const float* __restrict__ gamma,
                                                 u16* __restrict__ o) {
  const int row = blockIdx.x;
  const int t = threadIdx.x;
  float4 v = ((const float4*)(x + (size_t)row * 1024))[t];
  float ss = v.x * v.x + v.y * v.y + v.z * v.z + v.w * v.w;
  #pragma unroll
  for (int m = 1; m < 64; m <<= 1) ss += __shfl_xor(ss, m);
  __shared__ float wsum[4];
  if ((t & 63) == 0) wsum[t >> 6] = ss;
  __syncthreads();
  float tot = wsum[0] + wsum[1] + wsum[2] + wsum[3];
  float inv = rsqrtf(tot * (1.0f / 1024.0f) + 1e-5f);
  float4 g = ((const float4*)gamma)[t];
  u16x4 r;
  r.x = f2bf(v.x * inv * g.x);
  r.y = f2bf(v.y * inv * g.y);
  r.z = f2bf(v.z * inv * g.z);
  r.w = f2bf(v.w * inv * g.w);
  ((u16x4*)(o + (size_t)row * 1024))[t] = r;
}

// ========== 128x128 BK=64 single-buffer GEMM: C[M,N] = A[M,K]*B[N,K]^T =====
// 256 thr = 4 waves (2x2), 32KB LDS -> 4 blocks/CU: inter-block latency hiding
// (m97 mechanism). T2 chunk-XOR swizzle both-sides -> conflict-free ds_read.
// EPI 0: bf16 = acc * (gcol<ncut?scale:1)   (LDS-bounced coalesced stores)
// EPI 1: fp32 = acc + ep_fp32[idx]          (o-proj residual add)
// EPI 2: bf16 = silu(ep[idx]) * acc         (LDS-bounced)
// EPI 3: fp32 unsafeAtomicAdd(out+idx, acc) (split-K via blockIdx.z)
template <int EPI>
__global__ __launch_bounds__(256, 4)
void gemm128(const u16* __restrict__ A, const u16* __restrict__ B,
             void* out, const void* ep, int M, int N, int KLOOP, int KS,
             float scale, int ncut) {
  __shared__ u16 smem[2][8192];          // [A|B][128 rows x 64]; epilogue: C
  u16* const sA = smem[0];
  u16* const sB = smem[1];

  const int tid = threadIdx.x;
  const int lane = tid & 63;
  const int w = tid >> 6;
  const int wr = w >> 1, wc = w & 1;
  const int lr = lane & 15, lk = lane >> 4;

  A += (size_t)blockIdx.z * KLOOP;
  B += (size_t)blockIdx.z * KLOOP;

  // bijective XCD swizzle + 2D chunking (8 m-rows per super-row)
  const int nx = gridDim.x;
  const int nwg = nx * gridDim.y;
  const int flat = blockIdx.y * nx + blockIdx.x;
  const int qq = nwg >> 3, rr = nwg & 7;
  const int xcd = flat & 7, off = flat >> 3;
  const int swz = (xcd < rr ? xcd * (qq + 1) : rr * (qq + 1) + (xcd - rr) * qq) + off;
  const int sr = nx * 8;
  const int g8 = swz / sr, rem = swz % sr;
  const int m0 = (g8 * 8 + (rem & 7)) * 128;
  const int n0 = (rem >> 3) * 128;

  f32x4 acc[4][4];
  #pragma unroll
  for (int i = 0; i < 4; i++)
    #pragma unroll
    for (int j = 0; j < 4; j++) acc[i][j] = (f32x4){0.f, 0.f, 0.f, 0.f};

  // staging geometry: 1024 16B-chunks per operand, 4 per thread
  // chunk q -> row q>>3, pos q&7; source chunk (q&7)^(row&7)  [rule #21]
  for (int kt = 0; kt < KLOOP; kt += 64) {
    __syncthreads();
    #pragma unroll
    for (int r = 0; r < 4; r++) {
      const int q = r * 256 + tid;
      const int row = q >> 3;
      const int cs = (q & 7) ^ (row & 7);
      gload_lds16(A + (size_t)(m0 + row) * KS + kt + cs * 8, (char*)sA + q * 16);
      gload_lds16(B + (size_t)(n0 + row) * KS + kt + cs * 8, (char*)sB + q * 16);
    }
    __syncthreads();
    #pragma unroll
    for (int kk = 0; kk < 2; kk++) {
      bf16x8 a_[4], b_[4];
      #pragma unroll
      for (int i = 0; i < 4; i++)
        a_[i] = *(const bf16x8*)&sA[(wr * 64 + i * 16 + lr) * 64 +
                                    (((kk * 4 + lk) ^ (lr & 7)) * 8)];
      #pragma unroll
      for (int j = 0; j < 4; j++)
        b_[j] = *(const bf16x8*)&sB[(wc * 64 + j * 16 + lr) * 64 +
                                    (((kk * 4 + lk) ^ (lr & 7)) * 8)];
      #pragma unroll
      for (int i = 0; i < 4; i++)
        #pragma unroll
        for (int j = 0; j < 4; j++)
          acc[i][j] = __builtin_amdgcn_mfma_f32_16x16x32_bf16(a_[i], b_[j], acc[i][j], 0, 0, 0);
    }
  }

  if constexpr (EPI == 1 || EPI == 3) {
    #pragma unroll
    for (int i = 0; i < 4; i++)
      #pragma unroll
      for (int j = 0; j < 4; j++)
        #pragma unroll
        for (int r = 0; r < 4; r++) {
          const int grow = m0 + wr * 64 + i * 16 + lk * 4 + r;
          const int gcol = n0 + wc * 64 + j * 16 + lr;
          const size_t idx = (size_t)grow * N + gcol;
          if (EPI == 1) ((float*)out)[idx] = ((const float*)ep)[idx] + acc[i][j][r];
          else          unsafeAtomicAdd((float*)out + idx, acc[i][j][r]);
        }
  } else {
    // LDS-bounce to coalesced bf16 stores (smC = 128x128 over both smem bufs)
    u16* const smC = smem[0];
    const float s = (EPI == 0 && n0 < ncut) ? scale : 1.0f;
    __syncthreads();
    #pragma unroll
    for (int i = 0; i < 4; i++)
      #pragma unroll
      for (int j = 0; j < 4; j++)
        #pragma unroll
        for (int r = 0; r < 4; r++) {
          const int row = wr * 64 + i * 16 + lk * 4 + r;
          const int col = wc * 64 + j * 16 + lr;
          smC[row * 128 + (col ^ ((row & 7) << 3))] = f2bf(acc[i][j][r] * s);
        }
    __syncthreads();
    #pragma unroll
    for (int it = 0; it < 8; it++) {
      const int fl = it * 256 + tid;          // 2048 chunks
      const int row = fl >> 4;
      const int ch = fl & 15;
      bf16x8 cv = *(const bf16x8*)&smC[row * 128 + ((ch ^ (row & 7)) * 8)];
      const size_t gidx = (size_t)(m0 + row) * N + n0 + ch * 8;
      if (EPI == 0) {
        *(bf16x8*)((u16*)out + gidx) = cv;
      } else {
        bf16x8 gv = *(const bf16x8*)((const u16*)ep + gidx);
        bf16x8 ov;
        #pragma unroll
        for (int k = 0; k < 8; k++) {
          float g = bf2f((u16)gv[k]);
          float sg = g / (1.f + __expf(-g));
          ov[k] = (short)f2bf(sg * bf2f((u16)cv[k]));
        }
        *(bf16x8*)((u16*)out + gidx) = ov;
      }
    }
  }
}

// ---------------- V transpose from packed qkv: -> vt[bh=64][d=64][s=2048] ----
__global__ __launch_bounds__(256) void vtrans(const u16* __restrict__ qkv,
                                              u16* __restrict__ vt) {
  __shared__ u16 T[64][72];
  const int t = threadIdx.x;
  const int s0 = blockIdx.x * 64;
  const int h = blockIdx.y;
  const int b = blockIdx.z;
  const int sl = t >> 2, dl = (t & 3) * 16;
  const u16* src = qkv + ((size_t)(b * 2048 + s0 + sl)) * 3072 + 2048 + h * 64 + dl;
  bf16x8 v0 = *(const bf16x8*)src;
  bf16x8 v1 = *(const bf16x8*)(src + 8);
  #pragma unroll
  for (int j = 0; j < 8; j++) T[dl + j][sl] = (u16)v0[j];
  #pragma unroll
  for (int j = 0; j < 8; j++) T[dl + 8 + j][sl] = (u16)v1[j];
  __syncthreads();
  const int dl2 = t >> 2, sl2 = (t & 3) * 16;
  u16* dst = vt + ((size_t)((b * 16 + h) * 64 + dl2)) * 2048 + s0 + sl2;
  *(bf16x8*)dst = *(const bf16x8*)&T[dl2][sl2];
  *(bf16x8*)(dst + 8) = *(const bf16x8*)&T[dl2][sl2 + 8];
}

// ---------------- causal flash attention (packed qkv input) ----------------
__global__ __launch_bounds__(256)
void attn_fwd2(const u16* __restrict__ qkv, const u16* __restrict__ vt,
               u16* __restrict__ o) {
  __shared__ u16 sm[9216];
  u16* const smK = sm;
  u16* const smV = sm + 4096;

  const int tid = threadIdx.x;
  const int lane = tid & 63;
  const int w = tid >> 6;
  const int hi = lane >> 5;
  const int ln = lane & 31;

  const int flat = blockIdx.y * 16 + blockIdx.x;
  const int swz = (flat & 7) * 128 + (flat >> 3);
  const int qt = swz & 15;
  const int bh = swz >> 4;
  const int b = bh >> 4, h = bh & 15;

  const int qbase = qt * 128;
  const int qw0 = qbase + w * 32;
  const int qglob = qw0 + ln;
  const int nkb = qt * 2 + 2;

  bf16x8 qf[4];
  {
    const u16* qp = qkv + ((size_t)(b * 2048 + qw0 + ln)) * 3072 + h * 64 + hi * 8;
    #pragma unroll
    for (int c = 0; c < 4; c++) qf[c] = *(const bf16x8*)(qp + c * 16);
  }

  f32x16 accO[2];
  #pragma unroll
  for (int i = 0; i < 2; i++)
    #pragma unroll
    for (int r = 0; r < 16; r++) accO[i][r] = 0.f;
  float mrun = -1e30f, lsum = 0.f;

  for (int kb = 0; kb < nkb; kb++) {
    const int kbase = kb * 64;
    __syncthreads();
    #pragma unroll
    for (int r = 0; r < 2; r++) {
      const int cb = w * 128 + r * 64;
      const int ci = cb + lane;
      {
        const int key = ci >> 3, gch = (ci & 7) ^ (key & 7);
        const u16* src = qkv + ((size_t)(b * 2048 + kbase + key)) * 3072 + 1024 + h * 64 + gch * 8;
        gload_lds16(src, (char*)smK + cb * 16);
      }
      {
        const int d = ci >> 3, gch = (ci & 7) ^ (d & 7);
        const u16* src = vt + ((size_t)(bh * 64 + d)) * 2048 + kbase + gch * 8;
        gload_lds16(src, (char*)smV + cb * 16);
      }
    }
    __syncthreads();

    if (kbase <= qw0 + 31) {
      f32x16 st[2];
      #pragma unroll
      for (int kt = 0; kt < 2; kt++) {
        #pragma unroll
        for (int r = 0; r < 16; r++) st[kt][r] = 0.f;
        #pragma unroll
        for (int c = 0; c < 4; c++) {
          const int row = kt * 32 + ln;
          const int sch = (c * 2 + hi) ^ (ln & 7);
          bf16x8 kf = *(const bf16x8*)((const char*)smK + row * 128 + sch * 16);
          st[kt] = __builtin_amdgcn_mfma_f32_32x32x16_bf16(kf, qf[c], st[kt], 0, 0, 0);
        }
      }
      if (kbase + 63 > qw0) {
        #pragma unroll
        for (int kt = 0; kt < 2; kt++)
          #pragma unroll
          for (int r = 0; r < 16; r++) {
            const int kk = kbase + kt * 32 + (r & 3) + 8 * (r >> 2) + 4 * hi;
            if (kk > qglob) st[kt][r] = -1e30f;
          }
      }
      float pm = st[0][0];
      #pragma unroll
      for (int kt = 0; kt < 2; kt++)
        #pragma unroll
        for (int r = 0; r < 16; r++) pm = fmaxf(pm, st[kt][r]);
      pm = fmaxf(pm, __shfl_xor(pm, 32));
      const float mnew = fmaxf(mrun, pm);
      const float alpha = __expf(mrun - mnew);
      float ps = 0.f;
      #pragma unroll
      for (int kt = 0; kt < 2; kt++)
        #pragma unroll
        for (int r = 0; r < 16; r++) {
          const float p = __expf(st[kt][r] - mnew);
          st[kt][r] = p;
          ps += p;
        }
      ps += __shfl_xor(ps, 32);
      lsum = lsum * alpha + ps;
      mrun = mnew;
      accO[0] *= alpha;
      accO[1] *= alpha;

      #pragma unroll
      for (int kt = 0; kt < 2; kt++) {
        u32 pw[8], px[8];
        #pragma unroll
        for (int i = 0; i < 8; i++) pw[i] = pack2(st[kt][2 * i], st[kt][2 * i + 1]);
        #pragma unroll
        for (int i = 0; i < 8; i++) px[i] = (u32)__shfl_xor((int)pw[i], 32);
        union { u32 wd[4]; bf16x8 v; } f0, f1;
        f0.wd[0] = hi ? px[2] : pw[0];
        f0.wd[1] = hi ? px[3] : pw[1];
        f0.wd[2] = hi ? pw[2] : px[0];
        f0.wd[3] = hi ? pw[3] : px[1];
        f1.wd[0] = hi ? px[6] : pw[4];
        f1.wd[1] = hi ? px[7] : pw[5];
        f1.wd[2] = hi ? pw[6] : px[4];
        f1.wd[3] = hi ? pw[7] : px[5];
        #pragma unroll
        for (int d0 = 0; d0 < 2; d0++) {
          #pragma unroll
          for (int kc = 0; kc < 2; kc++) {
            const int drow = d0 * 32 + ln;
            const int sch = (kt * 4 + kc * 2 + hi) ^ (ln & 7);
            bf16x8 vf = *(const bf16x8*)((const char*)smV + drow * 128 + sch * 16);
            accO[d0] = __builtin_amdgcn_mfma_f32_32x32x16_bf16(vf, kc ? f1.v : f0.v,
                                                               accO[d0], 0, 0, 0);
          }
        }
      }
    }
  }

  __syncthreads();
  const float inv = 1.0f / lsum;
  #pragma unroll
  for (int d0 = 0; d0 < 2; d0++)
    #pragma unroll
    for (int r = 0; r < 16; r++) {
      const int d = d0 * 32 + (r & 3) + 8 * (r >> 2) + 4 * hi;
      sm[(w * 32 + ln) * 72 + d] = f2bf(accO[d0][r] * inv);
    }
  __syncthreads();
  const int ql = tid >> 1, dh = (tid & 1) * 32;
  const u16* srcp = &sm[ql * 72 + dh];
  u16* dst = o + ((size_t)(b * 2048 + qbase + ql)) * 1024 + h * 64 + dh;
  #pragma unroll
  for (int j = 0; j < 4; j++)
    *(bf16x8*)(dst + j * 8) = *(const bf16x8*)(srcp + j * 8);
}

// ---------------- host ----------------
extern "C" void kernel_launch(void* const* d_in, const int* in_sizes, int n_in,
                              void* d_out, int out_size, void* d_ws, size_t ws_size,
                              hipStream_t stream) {
  const float* x      = (const float*)d_in[0];
  const float* W_q    = (const float*)d_in[1];
  const float* W_k    = (const float*)d_in[2];
  const float* W_v    = (const float*)d_in[3];
  const float* W_o    = (const float*)d_in[4];
  const float* gamma1 = (const float*)d_in[5];
  const float* gamma2 = (const float*)d_in[6];
  const float* W1     = (const float*)d_in[7];
  const float* W2     = (const float*)d_in[8];
  const float* W3     = (const float*)d_in[9];

  char* ws = (char*)d_ws;
  const size_t MB = 1ull << 20;
  u16* qkvw  = (u16*)(ws + 0 * MB);    // Wq|Wk|Wv rows concat [3072][1024]
  u16* Wo_b  = (u16*)(ws + 6 * MB);
  u16* W1_b  = (u16*)(ws + 8 * MB);
  u16* W3_b  = (u16*)(ws + 16 * MB);
  u16* W2_b  = (u16*)(ws + 24 * MB);
  u16* xn    = (u16*)(ws + 32 * MB);   // 16 MB
  u16* qkvb  = (u16*)(ws + 48 * MB);   // [8192][3072] = 48 MB -> 48..96
  u16* attnb = (u16*)(ws + 96 * MB);   // 16 MB
  u16* vtb   = (u16*)(ws + 112 * MB);  // 16 MB (dead after attn)
  u16* gbuf  = (u16*)(ws + 112 * MB);  // 64 MB -> 112..176 (after attn)
  u16* hbuf  = (u16*)(ws + 48 * MB);   // 64 MB, reuses qkvb+attnb (dead)
  float* x1  = (float*)d_out;

  castw<<<1024, 256, 0, stream>>>(W_q, qkvw, 262144);
  castw<<<1024, 256, 0, stream>>>(W_k, qkvw + 1024 * 1024, 262144);
  castw<<<1024, 256, 0, stream>>>(W_v, qkvw + 2048 * 1024, 262144);
  castw<<<1024, 256, 0, stream>>>(W_o, Wo_b, 262144);
  castw<<<4096, 256, 0, stream>>>(W1, W1_b, 1048576);
  castw<<<4096, 256, 0, stream>>>(W3, W3_b, 1048576);
  castw<<<4096, 256, 0, stream>>>(W2, W2_b, 1048576);

  rmsnorm_k<<<8192, 256, 0, stream>>>(x, gamma1, xn);
  // QKV: 24x64 = 1536 wg
  gemm128<0><<<dim3(24, 64), 256, 0, stream>>>(xn, qkvw, qkvb, nullptr,
                                               8192, 3072, 1024, 1024, 0.125f, 1024);
  vtrans<<<dim3(32, 16, 4), 256, 0, stream>>>(qkvb, vtb);
  attn_fwd2<<<dim3(16, 64), 256, 0, stream>>>(qkvb, vtb, attnb);
  // o-proj: fp32 residual add
  gemm128<1><<<dim3(8, 64), 256, 0, stream>>>(attnb, Wo_b, x1, x,
                                              8192, 1024, 1024, 1024, 1.0f, 0);

  rmsnorm_k<<<8192, 256, 0, stream>>>(x1, gamma2, xn);
  gemm128<0><<<dim3(32, 64), 256, 0, stream>>>(xn, W1_b, gbuf, nullptr,
                                               8192, 4096, 1024, 1024, 1.0f, 0);
  gemm128<2><<<dim3(32, 64), 256, 0, stream>>>(xn, W3_b, hbuf, gbuf,
                                               8192, 4096, 1024, 1024, 1.0f, 0);
  // down-proj: split-K=2, fp32 atomic accumulate into d_out (holds x1)
  gemm128<3><<<dim3(8, 64, 2), 256, 0, stream>>>(hbuf, W2_b, (float*)d_out, nullptr,
                                                 8192, 1024, 2048, 4096, 1.0f, 0);
}

// Round 9
// 489.488 us; speedup vs baseline: 1.1525x; 1.0663x over previous
//
#include <hip/hip_runtime.h>
#include <cstdint>
#include <cstddef>

typedef unsigned short u16;
typedef unsigned int u32;
typedef short bf16x8 __attribute__((ext_vector_type(8)));
typedef float f32x4 __attribute__((ext_vector_type(4)));
typedef float f32x16 __attribute__((ext_vector_type(16)));
typedef u16 u16x4 __attribute__((ext_vector_type(4)));

__device__ __forceinline__ u16 f2bf(float f) {
  u32 u = __float_as_uint(f);
  return (u16)((u + 0x7FFFu + ((u >> 16) & 1u)) >> 16);
}
__device__ __forceinline__ float bf2f(u16 h) {
  return __uint_as_float(((u32)h) << 16);
}
// packed f32->bf16x2 (RNE), single instruction
__device__ __forceinline__ u32 cvtpk(float lo, float hi) {
  u32 r;
  asm("v_cvt_pk_bf16_f32 %0, %1, %2" : "=v"(r) : "v"(lo), "v"(hi));
  return r;
}
__device__ __forceinline__ float exp2a(float x) {
  float r;
  asm("v_exp_f32 %0, %1" : "=v"(r) : "v"(x));
  return r;
}

__device__ __forceinline__ void gload_lds16(const void* g, void* l) {
  __builtin_amdgcn_global_load_lds((const __attribute__((address_space(1))) u32*)g,
                                   (__attribute__((address_space(3))) u32*)l, 16, 0, 0);
}

// ---------------- weight cast fp32 -> bf16 ----------------
__global__ __launch_bounds__(256) void castw(const float* __restrict__ src,
                                             u16* __restrict__ dst, int n4) {
  int i = blockIdx.x * 256 + threadIdx.x;
  if (i < n4) {
    float4 v = ((const float4*)src)[i];
    u16x4 r;
    r.x = f2bf(v.x); r.y = f2bf(v.y); r.z = f2bf(v.z); r.w = f2bf(v.w);
    ((u16x4*)dst)[i] = r;
  }
}

// ---------------- RMSNorm: fp32 [rows,1024] -> bf16 ----------------
__global__ __launch_bounds__(256) void rmsnorm_k(const float* __restrict__ x,
                                                 const float* __restrict__ gamma,
                                                 u16* __restrict__ o) {
  const int row = blockIdx.x;
  const int t = threadIdx.x;
  float4 v = ((const float4*)(x + (size_t)row * 1024))[t];
  float ss = v.x * v.x + v.y * v.y + v.z * v.z + v.w * v.w;
  #pragma unroll
  for (int m = 1; m < 64; m <<= 1) ss += __shfl_xor(ss, m);
  __shared__ float wsum[4];
  if ((t & 63) == 0) wsum[t >> 6] = ss;
  __syncthreads();
  float tot = wsum[0] + wsum[1] + wsum[2] + wsum[3];
  float inv = rsqrtf(tot * (1.0f / 1024.0f) + 1e-5f);
  float4 g = ((const float4*)gamma)[t];
  u16x4 r;
  r.x = f2bf(v.x * inv * g.x);
  r.y = f2bf(v.y * inv * g.y);
  r.z = f2bf(v.z * inv * g.z);
  r.w = f2bf(v.w * inv * g.w);
  ((u16x4*)(o + (size_t)row * 1024))[t] = r;
}

// ========== 128x128 BK=64 single-buffer GEMM: C[M,N] = A[M,K]*B[N,K]^T =====
// 256 thr = 4 waves (2x2), 32KB LDS -> 4 blocks/CU (inter-block latency hiding)
template <int EPI>
__global__ __launch_bounds__(256, 4)
void gemm128(const u16* __restrict__ A, const u16* __restrict__ B,
             void* out, const void* ep, int M, int N, int KLOOP, int KS,
             float scale, int ncut) {
  __shared__ u16 smem[2][8192];
  u16* const sA = smem[0];
  u16* const sB = smem[1];

  const int tid = threadIdx.x;
  const int lane = tid & 63;
  const int w = tid >> 6;
  const int wr = w >> 1, wc = w & 1;
  const int lr = lane & 15, lk = lane >> 4;

  A += (size_t)blockIdx.z * KLOOP;
  B += (size_t)blockIdx.z * KLOOP;

  const int nx = gridDim.x;
  const int nwg = nx * gridDim.y;
  const int flat = blockIdx.y * nx + blockIdx.x;
  const int qq = nwg >> 3, rr = nwg & 7;
  const int xcd = flat & 7, off = flat >> 3;
  const int swz = (xcd < rr ? xcd * (qq + 1) : rr * (qq + 1) + (xcd - rr) * qq) + off;
  const int sr = nx * 8;
  const int g8 = swz / sr, rem = swz % sr;
  const int m0 = (g8 * 8 + (rem & 7)) * 128;
  const int n0 = (rem >> 3) * 128;

  f32x4 acc[4][4];
  #pragma unroll
  for (int i = 0; i < 4; i++)
    #pragma unroll
    for (int j = 0; j < 4; j++) acc[i][j] = (f32x4){0.f, 0.f, 0.f, 0.f};

  for (int kt = 0; kt < KLOOP; kt += 64) {
    __syncthreads();
    #pragma unroll
    for (int r = 0; r < 4; r++) {
      const int q = r * 256 + tid;
      const int row = q >> 3;
      const int cs = (q & 7) ^ (row & 7);
      gload_lds16(A + (size_t)(m0 + row) * KS + kt + cs * 8, (char*)sA + q * 16);
      gload_lds16(B + (size_t)(n0 + row) * KS + kt + cs * 8, (char*)sB + q * 16);
    }
    __syncthreads();
    #pragma unroll
    for (int kk = 0; kk < 2; kk++) {
      bf16x8 a_[4], b_[4];
      #pragma unroll
      for (int i = 0; i < 4; i++)
        a_[i] = *(const bf16x8*)&sA[(wr * 64 + i * 16 + lr) * 64 +
                                    (((kk * 4 + lk) ^ (lr & 7)) * 8)];
      #pragma unroll
      for (int j = 0; j < 4; j++)
        b_[j] = *(const bf16x8*)&sB[(wc * 64 + j * 16 + lr) * 64 +
                                    (((kk * 4 + lk) ^ (lr & 7)) * 8)];
      #pragma unroll
      for (int i = 0; i < 4; i++)
        #pragma unroll
        for (int j = 0; j < 4; j++)
          acc[i][j] = __builtin_amdgcn_mfma_f32_16x16x32_bf16(a_[i], b_[j], acc[i][j], 0, 0, 0);
    }
  }

  if constexpr (EPI == 1 || EPI == 3) {
    #pragma unroll
    for (int i = 0; i < 4; i++)
      #pragma unroll
      for (int j = 0; j < 4; j++)
        #pragma unroll
        for (int r = 0; r < 4; r++) {
          const int grow = m0 + wr * 64 + i * 16 + lk * 4 + r;
          const int gcol = n0 + wc * 64 + j * 16 + lr;
          const size_t idx = (size_t)grow * N + gcol;
          if (EPI == 1) ((float*)out)[idx] = ((const float*)ep)[idx] + acc[i][j][r];
          else          unsafeAtomicAdd((float*)out + idx, acc[i][j][r]);
        }
  } else {
    u16* const smC = smem[0];
    const float s = (EPI == 0 && n0 < ncut) ? scale : 1.0f;
    __syncthreads();
    #pragma unroll
    for (int i = 0; i < 4; i++)
      #pragma unroll
      for (int j = 0; j < 4; j++)
        #pragma unroll
        for (int r = 0; r < 4; r++) {
          const int row = wr * 64 + i * 16 + lk * 4 + r;
          const int col = wc * 64 + j * 16 + lr;
          smC[row * 128 + (col ^ ((row & 7) << 3))] = f2bf(acc[i][j][r] * s);
        }
    __syncthreads();
    #pragma unroll
    for (int it = 0; it < 8; it++) {
      const int fl = it * 256 + tid;
      const int row = fl >> 4;
      const int ch = fl & 15;
      bf16x8 cv = *(const bf16x8*)&smC[row * 128 + ((ch ^ (row & 7)) * 8)];
      const size_t gidx = (size_t)(m0 + row) * N + n0 + ch * 8;
      if (EPI == 0) {
        *(bf16x8*)((u16*)out + gidx) = cv;
      } else {
        bf16x8 gv = *(const bf16x8*)((const u16*)ep + gidx);
        bf16x8 ov;
        #pragma unroll
        for (int k = 0; k < 8; k++) {
          float g = bf2f((u16)gv[k]);
          float sg = g / (1.f + __expf(-g));
          ov[k] = (short)f2bf(sg * bf2f((u16)cv[k]));
        }
        *(bf16x8*)((u16*)out + gidx) = ov;
      }
    }
  }
}

// ---------------- V transpose from packed qkv: -> vt[bh=64][d=64][s=2048] ----
__global__ __launch_bounds__(256) void vtrans(const u16* __restrict__ qkv,
                                              u16* __restrict__ vt) {
  __shared__ u16 T[64][72];
  const int t = threadIdx.x;
  const int s0 = blockIdx.x * 64;
  const int h = blockIdx.y;
  const int b = blockIdx.z;
  const int sl = t >> 2, dl = (t & 3) * 16;
  const u16* src = qkv + ((size_t)(b * 2048 + s0 + sl)) * 3072 + 2048 + h * 64 + dl;
  bf16x8 v0 = *(const bf16x8*)src;
  bf16x8 v1 = *(const bf16x8*)(src + 8);
  #pragma unroll
  for (int j = 0; j < 8; j++) T[dl + j][sl] = (u16)v0[j];
  #pragma unroll
  for (int j = 0; j < 8; j++) T[dl + 8 + j][sl] = (u16)v1[j];
  __syncthreads();
  const int dl2 = t >> 2, sl2 = (t & 3) * 16;
  u16* dst = vt + ((size_t)((b * 16 + h) * 64 + dl2)) * 2048 + s0 + sl2;
  *(bf16x8*)dst = *(const bf16x8*)&T[dl2][sl2];
  *(bf16x8*)(dst + 8) = *(const bf16x8*)&T[dl2][sl2 + 8];
}

// ---------------- causal flash attention v3 ----------------
// Paired q-tiles (qt, 15-qt) per block -> uniform 34 k-tile units.
// grid (bh=64, pair=8): xcd = bh%8, K/V panels L2-resident per XCD.
// Softmax in exp2 domain (log2e folded into Q scale), defer-max THR=8,
// tree reductions, cvt_pk packing, setprio around MFMA.
__global__ __launch_bounds__(256, 2)
void attn_fwd3(const u16* __restrict__ qkv, const u16* __restrict__ vt,
               u16* __restrict__ o) {
  __shared__ u16 sm[9216];
  u16* const smK = sm;
  u16* const smV = sm + 4096;

  const int tid = threadIdx.x;
  const int lane = tid & 63;
  const int w = tid >> 6;
  const int hi = lane >> 5;
  const int ln = lane & 31;

  const int bh = blockIdx.x;
  const int pair = blockIdx.y;
  const int b = bh >> 4, h = bh & 15;

  #pragma unroll 1
  for (int phase = 0; phase < 2; ++phase) {
    const int qt = phase ? (15 - pair) : pair;
    const int qbase = qt * 128;
    const int qw0 = qbase + w * 32;
    const int qglob = qw0 + ln;
    const int nkb = qt * 2 + 2;

    bf16x8 qf[4];
    {
      const u16* qp = qkv + ((size_t)(b * 2048 + qw0 + ln)) * 3072 + h * 64 + hi * 8;
      #pragma unroll
      for (int c = 0; c < 4; c++) qf[c] = *(const bf16x8*)(qp + c * 16);
    }

    f32x16 accO[2];
    #pragma unroll
    for (int i = 0; i < 2; i++)
      #pragma unroll
      for (int r = 0; r < 16; r++) accO[i][r] = 0.f;
    float mrun = -1e30f, lsum = 0.f;

    for (int kb = 0; kb < nkb; kb++) {
      const int kbase = kb * 64;
      __syncthreads();
      #pragma unroll
      for (int r = 0; r < 2; r++) {
        const int cb = w * 128 + r * 64;
        const int ci = cb + lane;
        {
          const int key = ci >> 3, gch = (ci & 7) ^ (key & 7);
          const u16* src = qkv + ((size_t)(b * 2048 + kbase + key)) * 3072 + 1024 + h * 64 + gch * 8;
          gload_lds16(src, (char*)smK + cb * 16);
        }
        {
          const int d = ci >> 3, gch = (ci & 7) ^ (d & 7);
          const u16* src = vt + ((size_t)(bh * 64 + d)) * 2048 + kbase + gch * 8;
          gload_lds16(src, (char*)smV + cb * 16);
        }
      }
      __syncthreads();

      if (kbase <= qw0 + 31) {
        f32x16 st[2];
        #pragma unroll
        for (int kt = 0; kt < 2; kt++) {
          #pragma unroll
          for (int r = 0; r < 16; r++) st[kt][r] = 0.f;
        }
        __builtin_amdgcn_s_setprio(1);
        #pragma unroll
        for (int kt = 0; kt < 2; kt++)
          #pragma unroll
          for (int c = 0; c < 4; c++) {
            const int row = kt * 32 + ln;
            const int sch = (c * 2 + hi) ^ (ln & 7);
            bf16x8 kf = *(const bf16x8*)((const char*)smK + row * 128 + sch * 16);
            st[kt] = __builtin_amdgcn_mfma_f32_32x32x16_bf16(kf, qf[c], st[kt], 0, 0, 0);
          }
        __builtin_amdgcn_s_setprio(0);
        if (kbase + 63 > qw0) {
          #pragma unroll
          for (int kt = 0; kt < 2; kt++)
            #pragma unroll
            for (int r = 0; r < 16; r++) {
              const int kk = kbase + kt * 32 + (r & 3) + 8 * (r >> 2) + 4 * hi;
              if (kk > qglob) st[kt][r] = -1e30f;
            }
        }
        // tree max over 32 lane-local values
        float t16[16];
        #pragma unroll
        for (int i = 0; i < 16; i++) t16[i] = fmaxf(st[0][i], st[1][i]);
        #pragma unroll
        for (int s = 8; s > 0; s >>= 1)
          #pragma unroll
          for (int i = 0; i < 8; i++)
            if (i < s) t16[i] = fmaxf(t16[i], t16[i + s]);
        float pm = t16[0];
        pm = fmaxf(pm, __shfl_xor(pm, 32));
        // defer-max: rescale only when max grew past threshold (log2 units)
        if (!__all(pm - mrun <= 8.f)) {
          const float mnew = fmaxf(mrun, pm);
          const float alpha = exp2a(mrun - mnew);
          lsum *= alpha;
          accO[0] *= alpha;
          accO[1] *= alpha;
          mrun = mnew;
        }
        // p = exp2(S - m)
        #pragma unroll
        for (int kt = 0; kt < 2; kt++)
          #pragma unroll
          for (int r = 0; r < 16; r++) st[kt][r] = exp2a(st[kt][r] - mrun);
        // tree sum
        float s16[16];
        #pragma unroll
        for (int i = 0; i < 16; i++) s16[i] = st[0][i] + st[1][i];
        #pragma unroll
        for (int s = 8; s > 0; s >>= 1)
          #pragma unroll
          for (int i = 0; i < 8; i++)
            if (i < s) s16[i] = s16[i] + s16[i + s];
        float ps = s16[0];
        ps += __shfl_xor(ps, 32);
        lsum += ps;

        #pragma unroll
        for (int kt = 0; kt < 2; kt++) {
          u32 pw[8], px[8];
          #pragma unroll
          for (int i = 0; i < 8; i++) pw[i] = cvtpk(st[kt][2 * i], st[kt][2 * i + 1]);
          #pragma unroll
          for (int i = 0; i < 8; i++) px[i] = (u32)__shfl_xor((int)pw[i], 32);
          union { u32 wd[4]; bf16x8 v; } f0, f1;
          f0.wd[0] = hi ? px[2] : pw[0];
          f0.wd[1] = hi ? px[3] : pw[1];
          f0.wd[2] = hi ? pw[2] : px[0];
          f0.wd[3] = hi ? pw[3] : px[1];
          f1.wd[0] = hi ? px[6] : pw[4];
          f1.wd[1] = hi ? px[7] : pw[5];
          f1.wd[2] = hi ? pw[6] : px[4];
          f1.wd[3] = hi ? pw[7] : px[5];
          __builtin_amdgcn_s_setprio(1);
          #pragma unroll
          for (int d0 = 0; d0 < 2; d0++) {
            #pragma unroll
            for (int kc = 0; kc < 2; kc++) {
              const int drow = d0 * 32 + ln;
              const int sch = (kt * 4 + kc * 2 + hi) ^ (ln & 7);
              bf16x8 vf = *(const bf16x8*)((const char*)smV + drow * 128 + sch * 16);
              accO[d0] = __builtin_amdgcn_mfma_f32_32x32x16_bf16(vf, kc ? f1.v : f0.v,
                                                                 accO[d0], 0, 0, 0);
            }
          }
          __builtin_amdgcn_s_setprio(0);
        }
      }
    }

    __syncthreads();
    const float inv = 1.0f / lsum;
    #pragma unroll
    for (int d0 = 0; d0 < 2; d0++)
      #pragma unroll
      for (int r = 0; r < 16; r++) {
        const int d = d0 * 32 + (r & 3) + 8 * (r >> 2) + 4 * hi;
        sm[(w * 32 + ln) * 72 + d] = f2bf(accO[d0][r] * inv);
      }
    __syncthreads();
    const int ql = tid >> 1, dh = (tid & 1) * 32;
    const u16* srcp = &sm[ql * 72 + dh];
    u16* dst = o + ((size_t)(b * 2048 + qbase + ql)) * 1024 + h * 64 + dh;
    #pragma unroll
    for (int j = 0; j < 4; j++)
      *(bf16x8*)(dst + j * 8) = *(const bf16x8*)(srcp + j * 8);
    __syncthreads();
  }
}

// ---------------- host ----------------
extern "C" void kernel_launch(void* const* d_in, const int* in_sizes, int n_in,
                              void* d_out, int out_size, void* d_ws, size_t ws_size,
                              hipStream_t stream) {
  const float* x      = (const float*)d_in[0];
  const float* W_q    = (const float*)d_in[1];
  const float* W_k    = (const float*)d_in[2];
  const float* W_v    = (const float*)d_in[3];
  const float* W_o    = (const float*)d_in[4];
  const float* gamma1 = (const float*)d_in[5];
  const float* gamma2 = (const float*)d_in[6];
  const float* W1     = (const float*)d_in[7];
  const float* W2     = (const float*)d_in[8];
  const float* W3     = (const float*)d_in[9];

  char* ws = (char*)d_ws;
  const size_t MB = 1ull << 20;
  u16* qkvw  = (u16*)(ws + 0 * MB);    // Wq|Wk|Wv rows concat [3072][1024]
  u16* Wo_b  = (u16*)(ws + 6 * MB);
  u16* W1_b  = (u16*)(ws + 8 * MB);
  u16* W3_b  = (u16*)(ws + 16 * MB);
  u16* W2_b  = (u16*)(ws + 24 * MB);
  u16* xn    = (u16*)(ws + 32 * MB);   // 16 MB
  u16* qkvb  = (u16*)(ws + 48 * MB);   // [8192][3072] = 48 MB -> 48..96
  u16* attnb = (u16*)(ws + 96 * MB);   // 16 MB
  u16* vtb   = (u16*)(ws + 112 * MB);  // 16 MB (dead after attn)
  u16* gbuf  = (u16*)(ws + 112 * MB);  // 64 MB -> 112..176 (after attn)
  u16* hbuf  = (u16*)(ws + 48 * MB);   // 64 MB, reuses qkvb+attnb (dead)
  float* x1  = (float*)d_out;

  castw<<<1024, 256, 0, stream>>>(W_q, qkvw, 262144);
  castw<<<1024, 256, 0, stream>>>(W_k, qkvw + 1024 * 1024, 262144);
  castw<<<1024, 256, 0, stream>>>(W_v, qkvw + 2048 * 1024, 262144);
  castw<<<1024, 256, 0, stream>>>(W_o, Wo_b, 262144);
  castw<<<4096, 256, 0, stream>>>(W1, W1_b, 1048576);
  castw<<<4096, 256, 0, stream>>>(W3, W3_b, 1048576);
  castw<<<4096, 256, 0, stream>>>(W2, W2_b, 1048576);

  rmsnorm_k<<<8192, 256, 0, stream>>>(x, gamma1, xn);
  // QKV; q pre-scale = (1/8)*log2e so softmax runs in exp2 domain
  gemm128<0><<<dim3(24, 64), 256, 0, stream>>>(xn, qkvw, qkvb, nullptr,
                                               8192, 3072, 1024, 1024,
                                               0.125f * 1.44269504f, 1024);
  vtrans<<<dim3(32, 16, 4), 256, 0, stream>>>(qkvb, vtb);
  attn_fwd3<<<dim3(64, 8), 256, 0, stream>>>(qkvb, vtb, attnb);
  // o-proj: fp32 residual add
  gemm128<1><<<dim3(8, 64), 256, 0, stream>>>(attnb, Wo_b, x1, x,
                                              8192, 1024, 1024, 1024, 1.0f, 0);

  rmsnorm_k<<<8192, 256, 0, stream>>>(x1, gamma2, xn);
  gemm128<0><<<dim3(32, 64), 256, 0, stream>>>(xn, W1_b, gbuf, nullptr,
                                               8192, 4096, 1024, 1024, 1.0f, 0);
  gemm128<2><<<dim3(32, 64), 256, 0, stream>>>(xn, W3_b, hbuf, gbuf,
                                               8192, 4096, 1024, 1024, 1.0f, 0);
  // down-proj: split-K=2, fp32 atomic accumulate into d_out (holds x1)
  gemm128<3><<<dim3(8, 64, 2), 256, 0, stream>>>(hbuf, W2_b, (float*)d_out, nullptr,
                                                 8192, 1024, 2048, 4096, 1.0f, 0);
}